// Round 1
// baseline (226.367 us; speedup 1.0000x reference)
//
#include <hip/hip_runtime.h>
#include <hip/hip_bf16.h>
#include <stdint.h>

typedef __bf16 bf16_t;
typedef __bf16 bf16x8 __attribute__((ext_vector_type(8)));
typedef __bf16 bf16x4 __attribute__((ext_vector_type(4)));
typedef float f32x4 __attribute__((ext_vector_type(4)));

#define NFEAT 256   // feature dim (both layers)
#define KDIM  512   // concat K = 2*NFEAT
#define BM 128
#define BN 128
#define BK 64

__device__ __forceinline__ void gload_lds16(const void* g, void* l) {
  __builtin_amdgcn_global_load_lds(
      (const __attribute__((address_space(1))) unsigned int*)g,
      (__attribute__((address_space(3))) unsigned int*)l, 16, 0, 0);
}

// ---------------- graph prep ----------------

__global__ void k_zero_i32(int* p, int n) {
  int i = blockIdx.x * blockDim.x + threadIdx.x;
  if (i < n) p[i] = 0;
}

__global__ void k_count_deg(const int* __restrict__ dst, int* __restrict__ deg, int nE) {
  int i = blockIdx.x * blockDim.x + threadIdx.x;
  if (i < nE) atomicAdd(&deg[dst[i]], 1);
}

// single-block exclusive scan over mpad entries; also writes cursor & inv_deg
__global__ __launch_bounds__(1024) void k_scan(const int* __restrict__ deg,
                                               int* __restrict__ offsets,
                                               int* __restrict__ cursor,
                                               float* __restrict__ inv_deg,
                                               int n) {
  __shared__ int s[1024];
  __shared__ int carry_s;
  int tid = threadIdx.x;
  if (tid == 0) carry_s = 0;
  __syncthreads();
  for (int base = 0; base < n; base += 1024) {
    int i = base + tid;
    int d = (i < n) ? deg[i] : 0;
    s[tid] = d;
    __syncthreads();
    for (int off = 1; off < 1024; off <<= 1) {
      int v = (tid >= off) ? s[tid - off] : 0;
      __syncthreads();
      s[tid] += v;
      __syncthreads();
    }
    int excl = carry_s + s[tid] - d;   // exclusive prefix
    if (i < n) {
      offsets[i] = excl;
      cursor[i]  = excl;
      inv_deg[i] = 1.0f / (float)(d > 1 ? d : 1);
    }
    __syncthreads();
    if (tid == 1023) carry_s += s[1023];
    __syncthreads();
  }
}

__global__ void k_scatter(const int* __restrict__ src, const int* __restrict__ dst,
                          int* __restrict__ cursor, int* __restrict__ csr_src, int nE) {
  int i = blockIdx.x * blockDim.x + threadIdx.x;
  if (i < nE) {
    int pos = atomicAdd(&cursor[dst[i]], 1);
    csr_src[pos] = src[i];
  }
}

// ---------------- dtype prep ----------------

// WT[n][k] = k<256 ? Wself[k][n] : Wneigh[k-256][n]   (bf16, [256][512])
__global__ void k_prep_w(const float* __restrict__ Wself, const float* __restrict__ Wneigh,
                         bf16_t* __restrict__ WT) {
  int t = blockIdx.x * blockDim.x + threadIdx.x;   // 0 .. 256*512-1
  if (t >= NFEAT * KDIM) return;
  int n = t >> 9;        // /512
  int k = t & 511;
  float v = (k < NFEAT) ? Wself[k * NFEAT + n] : Wneigh[(k - NFEAT) * NFEAT + n];
  WT[t] = (bf16_t)v;
}

// features f32 -> Xcat1 cols 0..255 (bf16), zero pad rows
__global__ void k_cast_feat(const float* __restrict__ F, bf16_t* __restrict__ X,
                            int nNodes, int mpad) {
  int t = blockIdx.x * blockDim.x + threadIdx.x;   // one thread = 4 cols
  int n = t >> 6;
  int c = (t & 63) * 4;
  if (n >= mpad) return;
  float4 v = make_float4(0.f, 0.f, 0.f, 0.f);
  if (n < nNodes) v = *(const float4*)&F[(size_t)n * NFEAT + c];
  bf16x4 o;
  o[0] = (bf16_t)v.x; o[1] = (bf16_t)v.y; o[2] = (bf16_t)v.z; o[3] = (bf16_t)v.w;
  *(bf16x4*)&X[(size_t)n * KDIM + c] = o;
}

// ---------------- aggregation (gather-mean) ----------------
// one wave per node; Hin: rows of `instride` bf16, cols 0..255 valid.
// writes mean into Hout[n][256..511].
__global__ __launch_bounds__(64) void k_agg(const bf16_t* __restrict__ Hin,
                                            bf16_t* __restrict__ Hout,
                                            const int* __restrict__ csr_src,
                                            const int* __restrict__ offsets,
                                            const int* __restrict__ deg,
                                            const float* __restrict__ inv_deg,
                                            int instride, int outstride) {
  int n = blockIdx.x;
  int lane = threadIdx.x;          // 0..63, 4 cols each
  int beg = offsets[n];
  int cnt = deg[n];
  float a0 = 0.f, a1 = 0.f, a2 = 0.f, a3 = 0.f;
  int i = 0;
  for (; i + 1 < cnt; i += 2) {
    int s0 = csr_src[beg + i];
    int s1 = csr_src[beg + i + 1];
    bf16x4 v0 = *(const bf16x4*)&Hin[(size_t)s0 * instride + lane * 4];
    bf16x4 v1 = *(const bf16x4*)&Hin[(size_t)s1 * instride + lane * 4];
    a0 += (float)v0[0] + (float)v1[0];
    a1 += (float)v0[1] + (float)v1[1];
    a2 += (float)v0[2] + (float)v1[2];
    a3 += (float)v0[3] + (float)v1[3];
  }
  if (i < cnt) {
    int s0 = csr_src[beg + i];
    bf16x4 v0 = *(const bf16x4*)&Hin[(size_t)s0 * instride + lane * 4];
    a0 += (float)v0[0]; a1 += (float)v0[1]; a2 += (float)v0[2]; a3 += (float)v0[3];
  }
  float w = inv_deg[n];
  bf16x4 o;
  o[0] = (bf16_t)(a0 * w); o[1] = (bf16_t)(a1 * w);
  o[2] = (bf16_t)(a2 * w); o[3] = (bf16_t)(a3 * w);
  *(bf16x4*)&Hout[(size_t)n * outstride + NFEAT + lane * 4] = o;
}

// ---------------- GEMM: [mpad x 512] @ [512 x 256] -> bf16 out ----------------
// A: Xcat row-major [mpad][512] bf16.  BT: [256][512] bf16 (n-major).
// C[m][n] = sum_k A[m][k]*BT[n][k] (+bias, optional relu) -> Cout[m*ostride+n]
__global__ __launch_bounds__(256, 2) void k_gemm(const bf16_t* __restrict__ A,
                                                 const bf16_t* __restrict__ BT,
                                                 const float* __restrict__ bias,
                                                 bf16_t* __restrict__ Cout,
                                                 int ostride, int relu) {
  __shared__ __align__(16) bf16_t As[2][BM * BK];
  __shared__ __align__(16) bf16_t Bs[2][BN * BK];
  const int tid  = threadIdx.x;
  const int lane = tid & 63;
  const int wave = tid >> 6;
  const int wr = wave >> 1, wc = wave & 1;    // 2x2 waves, 64x64 each
  const int m0 = blockIdx.x * BM;
  const int n0 = blockIdx.y * BN;
  const int l15 = lane & 15;
  const int lk8 = (lane >> 4) * 8;

  f32x4 acc[4][4] = {};

  auto stage = [&](int buf, int kt) {
    const int k0 = kt * BK;
    #pragma unroll
    for (int i = 0; i < 4; ++i) {
      int idx = i * 256 + tid;
      int row = idx >> 3;          // /8 16B-chunks per row
      int c8  = (idx & 7) * 8;     // elem offset
      gload_lds16(A + (size_t)(m0 + row) * KDIM + k0 + c8,
                  (char*)&As[buf][0] + (i * 256 + wave * 64) * 16);
    }
    #pragma unroll
    for (int i = 0; i < 4; ++i) {
      int idx = i * 256 + tid;
      int row = idx >> 3;
      int c8  = (idx & 7) * 8;
      gload_lds16(BT + (size_t)(n0 + row) * KDIM + k0 + c8,
                  (char*)&Bs[buf][0] + (i * 256 + wave * 64) * 16);
    }
  };

  auto compute = [&](int buf) {
    #pragma unroll
    for (int kk = 0; kk < 2; ++kk) {
      bf16x8 af[4], bfr[4];
      #pragma unroll
      for (int m = 0; m < 4; ++m) {
        int row = wr * 64 + m * 16 + l15;
        af[m] = *(const bf16x8*)&As[buf][row * BK + kk * 32 + lk8];
      }
      #pragma unroll
      for (int n = 0; n < 4; ++n) {
        int col = wc * 64 + n * 16 + l15;
        bfr[n] = *(const bf16x8*)&Bs[buf][col * BK + kk * 32 + lk8];
      }
      #pragma unroll
      for (int m = 0; m < 4; ++m)
        #pragma unroll
        for (int n = 0; n < 4; ++n)
          acc[m][n] = __builtin_amdgcn_mfma_f32_16x16x32_bf16(af[m], bfr[n], acc[m][n], 0, 0, 0);
    }
  };

  stage(0, 0);
  __syncthreads();
  const int nt = KDIM / BK;   // 8
  int cur = 0;
  for (int t = 0; t < nt; ++t) {
    if (t + 1 < nt) stage(cur ^ 1, t + 1);
    compute(cur);
    __syncthreads();
    cur ^= 1;
  }

  // epilogue
  #pragma unroll
  for (int n = 0; n < 4; ++n) {
    int col = n0 + wc * 64 + n * 16 + l15;
    float bv = bias[col];
    #pragma unroll
    for (int m = 0; m < 4; ++m) {
      int rbase = m0 + wr * 64 + m * 16 + (lane >> 4) * 4;
      #pragma unroll
      for (int j = 0; j < 4; ++j) {
        float v = acc[m][n][j] + bv;
        if (relu) v = fmaxf(v, 0.f);
        Cout[(size_t)(rbase + j) * ostride + col] = (bf16_t)v;
      }
    }
  }
}

// ---------------- per-edge dot ----------------
__global__ __launch_bounds__(256) void k_edge_dot(const bf16_t* __restrict__ H,
                                                  const int* __restrict__ src,
                                                  const int* __restrict__ dst,
                                                  float* __restrict__ out, int nE) {
  int wid  = (blockIdx.x * blockDim.x + threadIdx.x) >> 6;
  int lane = threadIdx.x & 63;
  if (wid >= nE) return;
  int s = src[wid], d = dst[wid];
  bf16x4 a = *(const bf16x4*)&H[(size_t)s * NFEAT + lane * 4];
  bf16x4 b = *(const bf16x4*)&H[(size_t)d * NFEAT + lane * 4];
  float acc = (float)a[0] * (float)b[0] + (float)a[1] * (float)b[1] +
              (float)a[2] * (float)b[2] + (float)a[3] * (float)b[3];
  #pragma unroll
  for (int off = 32; off; off >>= 1) acc += __shfl_xor(acc, off, 64);
  if (lane == 0) out[wid] = acc;
}

// ---------------- launcher ----------------

extern "C" void kernel_launch(void* const* d_in, const int* in_sizes, int n_in,
                              void* d_out, int out_size, void* d_ws, size_t ws_size,
                              hipStream_t stream) {
  const float* features = (const float*)d_in[0];
  const int*   src      = (const int*)d_in[1];
  const int*   dst      = (const int*)d_in[2];
  const float* Wself1   = (const float*)d_in[3];
  const float* Wneigh1  = (const float*)d_in[4];
  const float* b1       = (const float*)d_in[5];
  const float* Wself2   = (const float*)d_in[6];
  const float* Wneigh2  = (const float*)d_in[7];
  const float* b2       = (const float*)d_in[8];
  float* score = (float*)d_out;

  const int nNodes = in_sizes[0] / NFEAT;       // 20000
  const int nE     = in_sizes[1];               // 320000
  const int mpad   = ((nNodes + BM - 1) / BM) * BM;  // 20096

  char* ws = (char*)d_ws;
  size_t off = 0;
  auto alloc = [&](size_t bytes) { char* p = ws + off; off += (bytes + 255) & ~(size_t)255; return p; };
  bf16_t* Xcat1   = (bf16_t*)alloc((size_t)mpad * KDIM * 2);
  bf16_t* Xcat2   = (bf16_t*)alloc((size_t)mpad * KDIM * 2);
  bf16_t* H2      = (bf16_t*)alloc((size_t)mpad * NFEAT * 2);
  bf16_t* WT1     = (bf16_t*)alloc((size_t)NFEAT * KDIM * 2);
  bf16_t* WT2     = (bf16_t*)alloc((size_t)NFEAT * KDIM * 2);
  int*    deg     = (int*)alloc((size_t)mpad * 4);
  int*    offsets = (int*)alloc((size_t)mpad * 4);
  int*    cursor  = (int*)alloc((size_t)mpad * 4);
  float*  inv_deg = (float*)alloc((size_t)mpad * 4);
  int*    csr_src = (int*)alloc((size_t)nE * 4);

  const int eb = (nE + 255) / 256;

  // graph prep
  k_zero_i32<<<(mpad + 255) / 256, 256, 0, stream>>>(deg, mpad);
  k_count_deg<<<eb, 256, 0, stream>>>(dst, deg, nE);
  k_scan<<<1, 1024, 0, stream>>>(deg, offsets, cursor, inv_deg, mpad);
  k_scatter<<<eb, 256, 0, stream>>>(src, dst, cursor, csr_src, nE);

  // dtype prep
  k_prep_w<<<(NFEAT * KDIM + 255) / 256, 256, 0, stream>>>(Wself1, Wneigh1, WT1);
  k_prep_w<<<(NFEAT * KDIM + 255) / 256, 256, 0, stream>>>(Wself2, Wneigh2, WT2);
  k_cast_feat<<<(mpad * 64 + 255) / 256, 256, 0, stream>>>(features, Xcat1, nNodes, mpad);

  // layer 1
  k_agg<<<mpad, 64, 0, stream>>>(Xcat1, Xcat1, csr_src, offsets, deg, inv_deg, KDIM, KDIM);
  dim3 ggrid(mpad / BM, NFEAT / BN);
  k_gemm<<<ggrid, 256, 0, stream>>>(Xcat1, WT1, b1, Xcat2, KDIM, 1);

  // layer 2
  k_agg<<<mpad, 64, 0, stream>>>(Xcat2, Xcat2, csr_src, offsets, deg, inv_deg, KDIM, KDIM);
  k_gemm<<<ggrid, 256, 0, stream>>>(Xcat2, WT2, b2, H2, NFEAT, 0);

  // edge scores
  k_edge_dot<<<(nE + 3) / 4, 256, 0, stream>>>(H2, src, dst, score, nE);
}

// Round 2
// 218.300 us; speedup vs baseline: 1.0370x; 1.0370x over previous
//
#include <hip/hip_runtime.h>
#include <hip/hip_bf16.h>
#include <stdint.h>

typedef __bf16 bf16_t;
typedef __bf16 bf16x8 __attribute__((ext_vector_type(8)));
typedef __bf16 bf16x4 __attribute__((ext_vector_type(4)));
typedef float f32x4 __attribute__((ext_vector_type(4)));

#define NFEAT 256   // feature dim (both layers)
#define KDIM  512   // concat K = 2*NFEAT
#define BM 128
#define BN 128
#define BK 64

__device__ __forceinline__ void gload_lds16(const void* g, void* l) {
  __builtin_amdgcn_global_load_lds(
      (const __attribute__((address_space(1))) unsigned int*)g,
      (__attribute__((address_space(3))) unsigned int*)l, 16, 0, 0);
}

// ---------------- graph prep ----------------

__global__ void k_count_deg(const int* __restrict__ dst, int* __restrict__ deg, int nE) {
  int i = blockIdx.x * blockDim.x + threadIdx.x;
  if (i < nE) atomicAdd(&deg[dst[i]], 1);
}

// single-block scan: per-thread serial prefix over cpt contiguous elems +
// one 1024-wide Hillis-Steele pass. Writes offsets, cursor, inv_deg.
__global__ __launch_bounds__(1024) void k_scan(const int* __restrict__ deg,
                                               int* __restrict__ offsets,
                                               int* __restrict__ cursor,
                                               float* __restrict__ inv_deg,
                                               int n) {
  __shared__ int s[1024];
  const int tid = threadIdx.x;
  const int cpt = (n + 1023) >> 10;       // elems per thread
  const int base = tid * cpt;
  int run = 0;
  for (int j = 0; j < cpt; ++j) {
    int i = base + j;
    run += (i < n) ? deg[i] : 0;
  }
  s[tid] = run;
  __syncthreads();
  for (int off = 1; off < 1024; off <<= 1) {
    int v = (tid >= off) ? s[tid - off] : 0;
    __syncthreads();
    s[tid] += v;
    __syncthreads();
  }
  int excl = s[tid] - run;                // exclusive prefix for this thread
  int run2 = 0;
  for (int j = 0; j < cpt; ++j) {
    int i = base + j;
    int d = (i < n) ? deg[i] : 0;
    if (i < n) {
      int o = excl + run2;
      offsets[i] = o;
      cursor[i]  = o;
      inv_deg[i] = 1.0f / (float)(d > 1 ? d : 1);
    }
    run2 += d;
  }
}

__global__ void k_scatter(const int* __restrict__ src, const int* __restrict__ dst,
                          int* __restrict__ cursor, int* __restrict__ csr_src, int nE) {
  int i = blockIdx.x * blockDim.x + threadIdx.x;
  if (i < nE) {
    int pos = atomicAdd(&cursor[dst[i]], 1);
    csr_src[pos] = src[i];
  }
}

// ---------------- dtype prep ----------------

// both layers in one launch: WT[l][n][k] = k<256 ? Wself_l[k][n] : Wneigh_l[k-256][n]
__global__ void k_prep_w(const float* __restrict__ Ws1, const float* __restrict__ Wn1,
                         const float* __restrict__ Ws2, const float* __restrict__ Wn2,
                         bf16_t* __restrict__ WT1, bf16_t* __restrict__ WT2) {
  int t = blockIdx.x * blockDim.x + threadIdx.x;   // 0 .. 2*256*512-1
  if (t >= 2 * NFEAT * KDIM) return;
  int layer = t >> 17;
  int r = t & (NFEAT * KDIM - 1);
  int n = r >> 9;
  int k = r & 511;
  const float* Ws = layer ? Ws2 : Ws1;
  const float* Wn = layer ? Wn2 : Wn1;
  float v = (k < NFEAT) ? Ws[k * NFEAT + n] : Wn[(k - NFEAT) * NFEAT + n];
  (layer ? WT2 : WT1)[r] = (bf16_t)v;
}

// features f32 -> Xcat1 cols 0..255 (bf16), zero pad rows
__global__ void k_cast_feat(const float* __restrict__ F, bf16_t* __restrict__ X,
                            int nNodes, int mpad) {
  int t = blockIdx.x * blockDim.x + threadIdx.x;   // one thread = 4 cols
  int n = t >> 6;
  int c = (t & 63) * 4;
  if (n >= mpad) return;
  float4 v = make_float4(0.f, 0.f, 0.f, 0.f);
  if (n < nNodes) v = *(const float4*)&F[(size_t)n * NFEAT + c];
  bf16x4 o;
  o[0] = (bf16_t)v.x; o[1] = (bf16_t)v.y; o[2] = (bf16_t)v.z; o[3] = (bf16_t)v.w;
  *(bf16x4*)&X[(size_t)n * KDIM + c] = o;
}

// ---------------- aggregation (gather-mean) ----------------
// one wave per node. lanes 0-31 handle even neighbors, 32-63 odd; each lane
// owns 8 cols (bf16x8 = 16B loads). Index loads pipelined one pair ahead.
__global__ __launch_bounds__(64) void k_agg(const bf16_t* __restrict__ Hin,
                                            bf16_t* __restrict__ Hout,
                                            const int* __restrict__ csr_src,
                                            const int* __restrict__ offsets,
                                            const int* __restrict__ deg,
                                            const float* __restrict__ inv_deg,
                                            int instride, int outstride) {
  const int n = blockIdx.x;
  const int lane = threadIdx.x;
  const int half = lane >> 5;
  const int l32 = lane & 31;
  const int beg = offsets[n];
  const int cnt = deg[n];
  const size_t colo = (size_t)l32 * 8;

  float acc[8] = {0.f, 0.f, 0.f, 0.f, 0.f, 0.f, 0.f, 0.f};

  int k0 = half;
  int s_cur = (k0 < cnt) ? csr_src[beg + k0] : -1;
  for (int i = 0; i < cnt; i += 2) {
    int k1 = i + 2 + half;
    int s_nxt = (k1 < cnt) ? csr_src[beg + k1] : -1;
    if (s_cur >= 0) {
      bf16x8 v = *(const bf16x8*)&Hin[(size_t)s_cur * instride + colo];
      #pragma unroll
      for (int j = 0; j < 8; ++j) acc[j] += (float)v[j];
    }
    s_cur = s_nxt;
  }

  // cross-half reduce
  #pragma unroll
  for (int j = 0; j < 8; ++j) acc[j] += __shfl_xor(acc[j], 32, 64);

  if (half == 0) {
    float w = inv_deg[n];
    bf16x8 o;
    #pragma unroll
    for (int j = 0; j < 8; ++j) o[j] = (bf16_t)(acc[j] * w);
    *(bf16x8*)&Hout[(size_t)n * outstride + NFEAT + colo] = o;
  }
}

// ---------------- GEMM: [mpad x 512] @ [512 x 256] -> bf16 out ----------------
__global__ __launch_bounds__(256, 2) void k_gemm(const bf16_t* __restrict__ A,
                                                 const bf16_t* __restrict__ BT,
                                                 const float* __restrict__ bias,
                                                 bf16_t* __restrict__ Cout,
                                                 int ostride, int relu) {
  __shared__ __align__(16) bf16_t As[2][BM * BK];
  __shared__ __align__(16) bf16_t Bs[2][BN * BK];
  const int tid  = threadIdx.x;
  const int lane = tid & 63;
  const int wave = tid >> 6;
  const int wr = wave >> 1, wc = wave & 1;    // 2x2 waves, 64x64 each
  const int m0 = blockIdx.x * BM;
  const int n0 = blockIdx.y * BN;
  const int l15 = lane & 15;
  const int lk8 = (lane >> 4) * 8;

  f32x4 acc[4][4] = {};

  auto stage = [&](int buf, int kt) {
    const int k0 = kt * BK;
    #pragma unroll
    for (int i = 0; i < 4; ++i) {
      int idx = i * 256 + tid;
      int row = idx >> 3;
      int c8  = (idx & 7) * 8;
      gload_lds16(A + (size_t)(m0 + row) * KDIM + k0 + c8,
                  (char*)&As[buf][0] + (i * 256 + wave * 64) * 16);
    }
    #pragma unroll
    for (int i = 0; i < 4; ++i) {
      int idx = i * 256 + tid;
      int row = idx >> 3;
      int c8  = (idx & 7) * 8;
      gload_lds16(BT + (size_t)(n0 + row) * KDIM + k0 + c8,
                  (char*)&Bs[buf][0] + (i * 256 + wave * 64) * 16);
    }
  };

  auto compute = [&](int buf) {
    #pragma unroll
    for (int kk = 0; kk < 2; ++kk) {
      bf16x8 af[4], bfr[4];
      #pragma unroll
      for (int m = 0; m < 4; ++m) {
        int row = wr * 64 + m * 16 + l15;
        af[m] = *(const bf16x8*)&As[buf][row * BK + kk * 32 + lk8];
      }
      #pragma unroll
      for (int n = 0; n < 4; ++n) {
        int col = wc * 64 + n * 16 + l15;
        bfr[n] = *(const bf16x8*)&Bs[buf][col * BK + kk * 32 + lk8];
      }
      #pragma unroll
      for (int m = 0; m < 4; ++m)
        #pragma unroll
        for (int n = 0; n < 4; ++n)
          acc[m][n] = __builtin_amdgcn_mfma_f32_16x16x32_bf16(af[m], bfr[n], acc[m][n], 0, 0, 0);
    }
  };

  stage(0, 0);
  __syncthreads();
  const int nt = KDIM / BK;   // 8
  int cur = 0;
  for (int t = 0; t < nt; ++t) {
    if (t + 1 < nt) stage(cur ^ 1, t + 1);
    compute(cur);
    __syncthreads();
    cur ^= 1;
  }

  #pragma unroll
  for (int n = 0; n < 4; ++n) {
    int col = n0 + wc * 64 + n * 16 + l15;
    float bv = bias[col];
    #pragma unroll
    for (int m = 0; m < 4; ++m) {
      int rbase = m0 + wr * 64 + m * 16 + (lane >> 4) * 4;
      #pragma unroll
      for (int j = 0; j < 4; ++j) {
        float v = acc[m][n][j] + bv;
        if (relu) v = fmaxf(v, 0.f);
        Cout[(size_t)(rbase + j) * ostride + col] = (bf16_t)v;
      }
    }
  }
}

// ---------------- per-edge dot via MFMA: diag(S @ D^T) ----------------
// one wave = 16 edges. A-frag: src row (lane&15); B-frag: dst row (lane&15);
// 8x mfma_16x16x32 over K=256; diagonal lanes ((l15>>2)==hi) store acc[l15&3].
__global__ __launch_bounds__(256) void k_edge_dot(const bf16_t* __restrict__ H,
                                                  const int* __restrict__ src,
                                                  const int* __restrict__ dst,
                                                  float* __restrict__ out, int nE) {
  const int wid  = (blockIdx.x * blockDim.x + threadIdx.x) >> 6;
  const int lane = threadIdx.x & 63;
  const int l15  = lane & 15;
  const int hi   = lane >> 4;
  const int e0   = wid * 16;
  if (e0 >= nE) return;
  int es = e0 + l15;
  if (es >= nE) es = nE - 1;          // clamp (loads only; store guarded)

  const int s = src[es], d = dst[es];
  const bf16_t* ps = H + (size_t)s * NFEAT + hi * 8;
  const bf16_t* pd = H + (size_t)d * NFEAT + hi * 8;

  f32x4 acc = {0.f, 0.f, 0.f, 0.f};
  #pragma unroll
  for (int ks = 0; ks < 8; ++ks) {
    bf16x8 a = *(const bf16x8*)(ps + ks * 32);
    bf16x8 b = *(const bf16x8*)(pd + ks * 32);
    acc = __builtin_amdgcn_mfma_f32_16x16x32_bf16(a, b, acc, 0, 0, 0);
  }

  // diagonal: C row = hi*4 + j, col = l15; row==col -> j = l15 - hi*4
  if ((l15 >> 2) == hi && (e0 + l15) < nE) {
    int j = l15 & 3;
    float v = acc[0];
    v = (j == 1) ? acc[1] : v;
    v = (j == 2) ? acc[2] : v;
    v = (j == 3) ? acc[3] : v;
    out[e0 + l15] = v;
  }
}

// ---------------- launcher ----------------

extern "C" void kernel_launch(void* const* d_in, const int* in_sizes, int n_in,
                              void* d_out, int out_size, void* d_ws, size_t ws_size,
                              hipStream_t stream) {
  const float* features = (const float*)d_in[0];
  const int*   src      = (const int*)d_in[1];
  const int*   dst      = (const int*)d_in[2];
  const float* Wself1   = (const float*)d_in[3];
  const float* Wneigh1  = (const float*)d_in[4];
  const float* b1       = (const float*)d_in[5];
  const float* Wself2   = (const float*)d_in[6];
  const float* Wneigh2  = (const float*)d_in[7];
  const float* b2       = (const float*)d_in[8];
  float* score = (float*)d_out;

  const int nNodes = in_sizes[0] / NFEAT;       // 20000
  const int nE     = in_sizes[1];               // 320000
  const int mpad   = ((nNodes + BM - 1) / BM) * BM;  // 20096

  char* ws = (char*)d_ws;
  size_t off = 0;
  auto alloc = [&](size_t bytes) { char* p = ws + off; off += (bytes + 255) & ~(size_t)255; return p; };
  bf16_t* Xcat1   = (bf16_t*)alloc((size_t)mpad * KDIM * 2);
  bf16_t* Xcat2   = (bf16_t*)alloc((size_t)mpad * KDIM * 2);
  bf16_t* H2      = (bf16_t*)alloc((size_t)mpad * NFEAT * 2);
  bf16_t* WT1     = (bf16_t*)alloc((size_t)NFEAT * KDIM * 2);
  bf16_t* WT2     = (bf16_t*)alloc((size_t)NFEAT * KDIM * 2);
  int*    deg     = (int*)alloc((size_t)mpad * 4);
  int*    offsets = (int*)alloc((size_t)mpad * 4);
  int*    cursor  = (int*)alloc((size_t)mpad * 4);
  float*  inv_deg = (float*)alloc((size_t)mpad * 4);
  int*    csr_src = (int*)alloc((size_t)nE * 4);

  const int eb = (nE + 255) / 256;

  // graph prep
  hipMemsetAsync(deg, 0, (size_t)mpad * 4, stream);
  k_count_deg<<<eb, 256, 0, stream>>>(dst, deg, nE);
  k_scan<<<1, 1024, 0, stream>>>(deg, offsets, cursor, inv_deg, mpad);
  k_scatter<<<eb, 256, 0, stream>>>(src, dst, cursor, csr_src, nE);

  // dtype prep
  k_prep_w<<<(2 * NFEAT * KDIM + 255) / 256, 256, 0, stream>>>(Wself1, Wneigh1,
                                                               Wself2, Wneigh2, WT1, WT2);
  k_cast_feat<<<(mpad * 64 + 255) / 256, 256, 0, stream>>>(features, Xcat1, nNodes, mpad);

  // layer 1
  k_agg<<<mpad, 64, 0, stream>>>(Xcat1, Xcat1, csr_src, offsets, deg, inv_deg, KDIM, KDIM);
  dim3 ggrid(mpad / BM, NFEAT / BN);
  k_gemm<<<ggrid, 256, 0, stream>>>(Xcat1, WT1, b1, Xcat2, KDIM, 1);

  // layer 2
  k_agg<<<mpad, 64, 0, stream>>>(Xcat2, Xcat2, csr_src, offsets, deg, inv_deg, KDIM, KDIM);
  k_gemm<<<ggrid, 256, 0, stream>>>(Xcat2, WT2, b2, H2, NFEAT, 0);

  // edge scores: one wave per 16 edges
  const int nWaves = (nE + 15) / 16;
  k_edge_dot<<<(nWaves + 3) / 4, 256, 0, stream>>>(H2, src, dst, score, nE);
}

// Round 3
// 178.495 us; speedup vs baseline: 1.2682x; 1.2230x over previous
//
#include <hip/hip_runtime.h>
#include <hip/hip_bf16.h>
#include <stdint.h>

typedef __bf16 bf16_t;
typedef __bf16 bf16x8 __attribute__((ext_vector_type(8)));
typedef __bf16 bf16x4 __attribute__((ext_vector_type(4)));
typedef float f32x4 __attribute__((ext_vector_type(4)));

#define NFEAT 256   // feature dim (both layers)
#define KDIM  512   // concat K = 2*NFEAT
#define BM 128
#define BN 128
#define BK 64

__device__ __forceinline__ void gload_lds16(const void* g, void* l) {
  __builtin_amdgcn_global_load_lds(
      (const __attribute__((address_space(1))) unsigned int*)g,
      (__attribute__((address_space(3))) unsigned int*)l, 16, 0, 0);
}

// ---------------- graph prep ----------------

__global__ void k_count_deg(const int* __restrict__ dst, int* __restrict__ deg, int nE) {
  int i = blockIdx.x * blockDim.x + threadIdx.x;
  if (i < nE) atomicAdd(&deg[dst[i]], 1);
}

// ---- device-wide scan, 3 kernels (reduce -> scan partials -> local scan) ----

// block sums: partial[b] = sum(deg[b*256 .. b*256+255])
__global__ __launch_bounds__(256) void k_scan_part(const int* __restrict__ deg,
                                                   int* __restrict__ partial, int n) {
  const int tid = threadIdx.x;
  int i = blockIdx.x * 256 + tid;
  int d = (i < n) ? deg[i] : 0;
  #pragma unroll
  for (int off = 32; off; off >>= 1) d += __shfl_xor(d, off, 64);
  __shared__ int ws[4];
  if ((tid & 63) == 0) ws[tid >> 6] = d;
  __syncthreads();
  if (tid == 0) partial[blockIdx.x] = ws[0] + ws[1] + ws[2] + ws[3];
}

// single small block: exclusive scan of partials in place (nb <= 256)
__global__ __launch_bounds__(256) void k_scan_mid(int* __restrict__ partial, int nb) {
  __shared__ int s[256];
  const int tid = threadIdx.x;
  int d = (tid < nb) ? partial[tid] : 0;
  s[tid] = d;
  __syncthreads();
  for (int off = 1; off < 256; off <<= 1) {
    int v = (tid >= off) ? s[tid - off] : 0;
    __syncthreads();
    s[tid] += v;
    __syncthreads();
  }
  if (tid < nb) partial[tid] = s[tid] - d;   // exclusive
}

// per-block local scan + partial offset -> offsets/cursor/inv_deg
__global__ __launch_bounds__(256) void k_scan_final(const int* __restrict__ deg,
                                                    const int* __restrict__ partial,
                                                    int* __restrict__ offsets,
                                                    int* __restrict__ cursor,
                                                    float* __restrict__ inv_deg, int n) {
  __shared__ int s[256];
  const int tid = threadIdx.x;
  int i = blockIdx.x * 256 + tid;
  int d = (i < n) ? deg[i] : 0;
  s[tid] = d;
  __syncthreads();
  for (int off = 1; off < 256; off <<= 1) {
    int v = (tid >= off) ? s[tid - off] : 0;
    __syncthreads();
    s[tid] += v;
    __syncthreads();
  }
  if (i < n) {
    int excl = partial[blockIdx.x] + s[tid] - d;
    offsets[i] = excl;
    cursor[i]  = excl;
    inv_deg[i] = 1.0f / (float)(d > 1 ? d : 1);
  }
}

__global__ void k_scatter(const int* __restrict__ src, const int* __restrict__ dst,
                          int* __restrict__ cursor, int* __restrict__ csr_src, int nE) {
  int i = blockIdx.x * blockDim.x + threadIdx.x;
  if (i < nE) {
    int pos = atomicAdd(&cursor[dst[i]], 1);
    csr_src[pos] = src[i];
  }
}

// ---------------- dtype prep ----------------

// both layers in one launch: WT[l][n][k] = k<256 ? Wself_l[k][n] : Wneigh_l[k-256][n]
__global__ void k_prep_w(const float* __restrict__ Ws1, const float* __restrict__ Wn1,
                         const float* __restrict__ Ws2, const float* __restrict__ Wn2,
                         bf16_t* __restrict__ WT1, bf16_t* __restrict__ WT2) {
  int t = blockIdx.x * blockDim.x + threadIdx.x;   // 0 .. 2*256*512-1
  if (t >= 2 * NFEAT * KDIM) return;
  int layer = t >> 17;
  int r = t & (NFEAT * KDIM - 1);
  int n = r >> 9;
  int k = r & 511;
  const float* Ws = layer ? Ws2 : Ws1;
  const float* Wn = layer ? Wn2 : Wn1;
  float v = (k < NFEAT) ? Ws[k * NFEAT + n] : Wn[(k - NFEAT) * NFEAT + n];
  (layer ? WT2 : WT1)[r] = (bf16_t)v;
}

// features f32 -> Xcat1 cols 0..255 (bf16), zero pad rows
__global__ void k_cast_feat(const float* __restrict__ F, bf16_t* __restrict__ X,
                            int nNodes, int mpad) {
  int t = blockIdx.x * blockDim.x + threadIdx.x;   // one thread = 4 cols
  int n = t >> 6;
  int c = (t & 63) * 4;
  if (n >= mpad) return;
  float4 v = make_float4(0.f, 0.f, 0.f, 0.f);
  if (n < nNodes) v = *(const float4*)&F[(size_t)n * NFEAT + c];
  bf16x4 o;
  o[0] = (bf16_t)v.x; o[1] = (bf16_t)v.y; o[2] = (bf16_t)v.z; o[3] = (bf16_t)v.w;
  *(bf16x4*)&X[(size_t)n * KDIM + c] = o;
}

// ---------------- aggregation (gather-mean) ----------------
// one wave per node. lanes 0-31 handle even neighbors, 32-63 odd; each lane
// owns 8 cols (bf16x8 = 16B loads). Index loads pipelined one pair ahead.
__global__ __launch_bounds__(64) void k_agg(const bf16_t* __restrict__ Hin,
                                            bf16_t* __restrict__ Hout,
                                            const int* __restrict__ csr_src,
                                            const int* __restrict__ offsets,
                                            const int* __restrict__ deg,
                                            const float* __restrict__ inv_deg,
                                            int instride, int outstride) {
  const int n = blockIdx.x;
  const int lane = threadIdx.x;
  const int half = lane >> 5;
  const int l32 = lane & 31;
  const int beg = offsets[n];
  const int cnt = deg[n];
  const size_t colo = (size_t)l32 * 8;

  float acc[8] = {0.f, 0.f, 0.f, 0.f, 0.f, 0.f, 0.f, 0.f};

  int k0 = half;
  int s_cur = (k0 < cnt) ? csr_src[beg + k0] : -1;
  for (int i = 0; i < cnt; i += 2) {
    int k1 = i + 2 + half;
    int s_nxt = (k1 < cnt) ? csr_src[beg + k1] : -1;
    if (s_cur >= 0) {
      bf16x8 v = *(const bf16x8*)&Hin[(size_t)s_cur * instride + colo];
      #pragma unroll
      for (int j = 0; j < 8; ++j) acc[j] += (float)v[j];
    }
    s_cur = s_nxt;
  }

  // cross-half reduce
  #pragma unroll
  for (int j = 0; j < 8; ++j) acc[j] += __shfl_xor(acc[j], 32, 64);

  if (half == 0) {
    float w = inv_deg[n];
    bf16x8 o;
    #pragma unroll
    for (int j = 0; j < 8; ++j) o[j] = (bf16_t)(acc[j] * w);
    *(bf16x8*)&Hout[(size_t)n * outstride + NFEAT + colo] = o;
  }
}

// ---------------- GEMM: [mpad x 512] @ [512 x 256] -> bf16 out ----------------
__global__ __launch_bounds__(256, 2) void k_gemm(const bf16_t* __restrict__ A,
                                                 const bf16_t* __restrict__ BT,
                                                 const float* __restrict__ bias,
                                                 bf16_t* __restrict__ Cout,
                                                 int ostride, int relu) {
  __shared__ __align__(16) bf16_t As[2][BM * BK];
  __shared__ __align__(16) bf16_t Bs[2][BN * BK];
  const int tid  = threadIdx.x;
  const int lane = tid & 63;
  const int wave = tid >> 6;
  const int wr = wave >> 1, wc = wave & 1;    // 2x2 waves, 64x64 each
  const int m0 = blockIdx.x * BM;
  const int n0 = blockIdx.y * BN;
  const int l15 = lane & 15;
  const int lk8 = (lane >> 4) * 8;

  f32x4 acc[4][4] = {};

  auto stage = [&](int buf, int kt) {
    const int k0 = kt * BK;
    #pragma unroll
    for (int i = 0; i < 4; ++i) {
      int idx = i * 256 + tid;
      int row = idx >> 3;
      int c8  = (idx & 7) * 8;
      gload_lds16(A + (size_t)(m0 + row) * KDIM + k0 + c8,
                  (char*)&As[buf][0] + (i * 256 + wave * 64) * 16);
    }
    #pragma unroll
    for (int i = 0; i < 4; ++i) {
      int idx = i * 256 + tid;
      int row = idx >> 3;
      int c8  = (idx & 7) * 8;
      gload_lds16(BT + (size_t)(n0 + row) * KDIM + k0 + c8,
                  (char*)&Bs[buf][0] + (i * 256 + wave * 64) * 16);
    }
  };

  auto compute = [&](int buf) {
    #pragma unroll
    for (int kk = 0; kk < 2; ++kk) {
      bf16x8 af[4], bfr[4];
      #pragma unroll
      for (int m = 0; m < 4; ++m) {
        int row = wr * 64 + m * 16 + l15;
        af[m] = *(const bf16x8*)&As[buf][row * BK + kk * 32 + lk8];
      }
      #pragma unroll
      for (int n = 0; n < 4; ++n) {
        int col = wc * 64 + n * 16 + l15;
        bfr[n] = *(const bf16x8*)&Bs[buf][col * BK + kk * 32 + lk8];
      }
      #pragma unroll
      for (int m = 0; m < 4; ++m)
        #pragma unroll
        for (int n = 0; n < 4; ++n)
          acc[m][n] = __builtin_amdgcn_mfma_f32_16x16x32_bf16(af[m], bfr[n], acc[m][n], 0, 0, 0);
    }
  };

  stage(0, 0);
  __syncthreads();
  const int nt = KDIM / BK;   // 8
  int cur = 0;
  for (int t = 0; t < nt; ++t) {
    if (t + 1 < nt) stage(cur ^ 1, t + 1);
    compute(cur);
    __syncthreads();
    cur ^= 1;
  }

  #pragma unroll
  for (int n = 0; n < 4; ++n) {
    int col = n0 + wc * 64 + n * 16 + l15;
    float bv = bias[col];
    #pragma unroll
    for (int m = 0; m < 4; ++m) {
      int rbase = m0 + wr * 64 + m * 16 + (lane >> 4) * 4;
      #pragma unroll
      for (int j = 0; j < 4; ++j) {
        float v = acc[m][n][j] + bv;
        if (relu) v = fmaxf(v, 0.f);
        Cout[(size_t)(rbase + j) * ostride + col] = (bf16_t)v;
      }
    }
  }
}

// ---------------- per-edge dot via MFMA: diag(S @ D^T) ----------------
// one wave = 16 edges. A-frag: src row (lane&15); B-frag: dst row (lane&15);
// 8x mfma_16x16x32 over K=256; diagonal lanes ((l15>>2)==hi) store acc[l15&3].
__global__ __launch_bounds__(256) void k_edge_dot(const bf16_t* __restrict__ H,
                                                  const int* __restrict__ src,
                                                  const int* __restrict__ dst,
                                                  float* __restrict__ out, int nE) {
  const int wid  = (blockIdx.x * blockDim.x + threadIdx.x) >> 6;
  const int lane = threadIdx.x & 63;
  const int l15  = lane & 15;
  const int hi   = lane >> 4;
  const int e0   = wid * 16;
  if (e0 >= nE) return;
  int es = e0 + l15;
  if (es >= nE) es = nE - 1;          // clamp (loads only; store guarded)

  const int s = src[es], d = dst[es];
  const bf16_t* ps = H + (size_t)s * NFEAT + hi * 8;
  const bf16_t* pd = H + (size_t)d * NFEAT + hi * 8;

  f32x4 acc = {0.f, 0.f, 0.f, 0.f};
  #pragma unroll
  for (int ks = 0; ks < 8; ++ks) {
    bf16x8 a = *(const bf16x8*)(ps + ks * 32);
    bf16x8 b = *(const bf16x8*)(pd + ks * 32);
    acc = __builtin_amdgcn_mfma_f32_16x16x32_bf16(a, b, acc, 0, 0, 0);
  }

  // diagonal: C row = hi*4 + j, col = l15; row==col -> j = l15 - hi*4
  if ((l15 >> 2) == hi && (e0 + l15) < nE) {
    int j = l15 & 3;
    float v = acc[0];
    v = (j == 1) ? acc[1] : v;
    v = (j == 2) ? acc[2] : v;
    v = (j == 3) ? acc[3] : v;
    out[e0 + l15] = v;
  }
}

// ---------------- launcher ----------------

extern "C" void kernel_launch(void* const* d_in, const int* in_sizes, int n_in,
                              void* d_out, int out_size, void* d_ws, size_t ws_size,
                              hipStream_t stream) {
  const float* features = (const float*)d_in[0];
  const int*   src      = (const int*)d_in[1];
  const int*   dst      = (const int*)d_in[2];
  const float* Wself1   = (const float*)d_in[3];
  const float* Wneigh1  = (const float*)d_in[4];
  const float* b1       = (const float*)d_in[5];
  const float* Wself2   = (const float*)d_in[6];
  const float* Wneigh2  = (const float*)d_in[7];
  const float* b2       = (const float*)d_in[8];
  float* score = (float*)d_out;

  const int nNodes = in_sizes[0] / NFEAT;       // 20000
  const int nE     = in_sizes[1];               // 320000
  const int mpad   = ((nNodes + BM - 1) / BM) * BM;  // 20096

  char* ws = (char*)d_ws;
  size_t off = 0;
  auto alloc = [&](size_t bytes) { char* p = ws + off; off += (bytes + 255) & ~(size_t)255; return p; };
  bf16_t* Xcat1   = (bf16_t*)alloc((size_t)mpad * KDIM * 2);
  bf16_t* Xcat2   = (bf16_t*)alloc((size_t)mpad * KDIM * 2);
  bf16_t* H2      = (bf16_t*)alloc((size_t)mpad * NFEAT * 2);
  bf16_t* WT1     = (bf16_t*)alloc((size_t)NFEAT * KDIM * 2);
  bf16_t* WT2     = (bf16_t*)alloc((size_t)NFEAT * KDIM * 2);
  int*    deg     = (int*)alloc((size_t)mpad * 4);
  int*    offsets = (int*)alloc((size_t)mpad * 4);
  int*    cursor  = (int*)alloc((size_t)mpad * 4);
  float*  inv_deg = (float*)alloc((size_t)mpad * 4);
  int*    csr_src = (int*)alloc((size_t)nE * 4);
  int*    partial = (int*)alloc(1024 * 4);

  const int eb = (nE + 255) / 256;
  const int nb = (mpad + 255) / 256;     // 79 scan blocks

  // graph prep
  hipMemsetAsync(deg, 0, (size_t)mpad * 4, stream);
  k_count_deg<<<eb, 256, 0, stream>>>(dst, deg, nE);
  k_scan_part<<<nb, 256, 0, stream>>>(deg, partial, mpad);
  k_scan_mid<<<1, 256, 0, stream>>>(partial, nb);
  k_scan_final<<<nb, 256, 0, stream>>>(deg, partial, offsets, cursor, inv_deg, mpad);
  k_scatter<<<eb, 256, 0, stream>>>(src, dst, cursor, csr_src, nE);

  // dtype prep
  k_prep_w<<<(2 * NFEAT * KDIM + 255) / 256, 256, 0, stream>>>(Wself1, Wneigh1,
                                                               Wself2, Wneigh2, WT1, WT2);
  k_cast_feat<<<(mpad * 64 + 255) / 256, 256, 0, stream>>>(features, Xcat1, nNodes, mpad);

  // layer 1
  k_agg<<<mpad, 64, 0, stream>>>(Xcat1, Xcat1, csr_src, offsets, deg, inv_deg, KDIM, KDIM);
  dim3 ggrid(mpad / BM, NFEAT / BN);
  k_gemm<<<ggrid, 256, 0, stream>>>(Xcat1, WT1, b1, Xcat2, KDIM, 1);

  // layer 2
  k_agg<<<mpad, 64, 0, stream>>>(Xcat2, Xcat2, csr_src, offsets, deg, inv_deg, KDIM, KDIM);
  k_gemm<<<ggrid, 256, 0, stream>>>(Xcat2, WT2, b2, H2, NFEAT, 0);

  // edge scores: one wave per 16 edges
  const int nWaves = (nE + 15) / 16;
  k_edge_dot<<<(nWaves + 3) / 4, 256, 0, stream>>>(H2, src, dst, score, nE);
}

// Round 4
// 175.064 us; speedup vs baseline: 1.2930x; 1.0196x over previous
//
#include <hip/hip_runtime.h>
#include <hip/hip_bf16.h>
#include <stdint.h>

typedef __bf16 bf16_t;
typedef __bf16 bf16x8 __attribute__((ext_vector_type(8)));
typedef __bf16 bf16x4 __attribute__((ext_vector_type(4)));
typedef float f32x4 __attribute__((ext_vector_type(4)));

#define NFEAT 256   // feature dim (both layers)
#define KDIM  512   // concat K = 2*NFEAT
#define BM 128
#define BN 128
#define BK 64

__device__ __forceinline__ void gload_lds16(const void* g, void* l) {
  __builtin_amdgcn_global_load_lds(
      (const __attribute__((address_space(1))) unsigned int*)g,
      (__attribute__((address_space(3))) unsigned int*)l, 16, 0, 0);
}

// ---------------- graph prep ----------------

__global__ void k_count_deg(const int* __restrict__ dst, int* __restrict__ deg, int nE) {
  int i = blockIdx.x * blockDim.x + threadIdx.x;
  if (i < nE) atomicAdd(&deg[dst[i]], 1);
}

// ---- device-wide scan, 3 kernels (reduce -> scan partials -> local scan) ----

// block sums: partial[b] = sum(deg[b*256 .. b*256+255])
__global__ __launch_bounds__(256) void k_scan_part(const int* __restrict__ deg,
                                                   int* __restrict__ partial, int n) {
  const int tid = threadIdx.x;
  int i = blockIdx.x * 256 + tid;
  int d = (i < n) ? deg[i] : 0;
  #pragma unroll
  for (int off = 32; off; off >>= 1) d += __shfl_xor(d, off, 64);
  __shared__ int ws[4];
  if ((tid & 63) == 0) ws[tid >> 6] = d;
  __syncthreads();
  if (tid == 0) partial[blockIdx.x] = ws[0] + ws[1] + ws[2] + ws[3];
}

// single small block: exclusive scan of partials in place (nb <= 256)
__global__ __launch_bounds__(256) void k_scan_mid(int* __restrict__ partial, int nb) {
  __shared__ int s[256];
  const int tid = threadIdx.x;
  int d = (tid < nb) ? partial[tid] : 0;
  s[tid] = d;
  __syncthreads();
  for (int off = 1; off < 256; off <<= 1) {
    int v = (tid >= off) ? s[tid - off] : 0;
    __syncthreads();
    s[tid] += v;
    __syncthreads();
  }
  if (tid < nb) partial[tid] = s[tid] - d;   // exclusive
}

// per-block local scan + partial offset -> offsets/cursor/inv_deg
__global__ __launch_bounds__(256) void k_scan_final(const int* __restrict__ deg,
                                                    const int* __restrict__ partial,
                                                    int* __restrict__ offsets,
                                                    int* __restrict__ cursor,
                                                    float* __restrict__ inv_deg, int n) {
  __shared__ int s[256];
  const int tid = threadIdx.x;
  int i = blockIdx.x * 256 + tid;
  int d = (i < n) ? deg[i] : 0;
  s[tid] = d;
  __syncthreads();
  for (int off = 1; off < 256; off <<= 1) {
    int v = (tid >= off) ? s[tid - off] : 0;
    __syncthreads();
    s[tid] += v;
    __syncthreads();
  }
  if (i < n) {
    int excl = partial[blockIdx.x] + s[tid] - d;
    offsets[i] = excl;
    cursor[i]  = excl;
    inv_deg[i] = 1.0f / (float)(d > 1 ? d : 1);
  }
}

__global__ void k_scatter(const int* __restrict__ src, const int* __restrict__ dst,
                          int* __restrict__ cursor, int* __restrict__ csr_src, int nE) {
  int i = blockIdx.x * blockDim.x + threadIdx.x;
  if (i < nE) {
    int pos = atomicAdd(&cursor[dst[i]], 1);
    csr_src[pos] = src[i];
  }
}

// ---------------- dtype prep ----------------

// both layers in one launch: WT[l][n][k] = k<256 ? Wself_l[k][n] : Wneigh_l[k-256][n]
// ALSO zeroes deg[] (runs before k_count_deg) — replaces a 42us runtime memset.
__global__ void k_prep_w(const float* __restrict__ Ws1, const float* __restrict__ Wn1,
                         const float* __restrict__ Ws2, const float* __restrict__ Wn2,
                         bf16_t* __restrict__ WT1, bf16_t* __restrict__ WT2,
                         int* __restrict__ deg, int mpad) {
  int t = blockIdx.x * blockDim.x + threadIdx.x;   // 0 .. 2*256*512-1
  if (t < mpad) deg[t] = 0;
  if (t >= 2 * NFEAT * KDIM) return;
  int layer = t >> 17;
  int r = t & (NFEAT * KDIM - 1);
  int n = r >> 9;
  int k = r & 511;
  const float* Ws = layer ? Ws2 : Ws1;
  const float* Wn = layer ? Wn2 : Wn1;
  float v = (k < NFEAT) ? Ws[k * NFEAT + n] : Wn[(k - NFEAT) * NFEAT + n];
  (layer ? WT2 : WT1)[r] = (bf16_t)v;
}

// features f32 -> Xcat1 cols 0..255 (bf16), zero pad rows
__global__ void k_cast_feat(const float* __restrict__ F, bf16_t* __restrict__ X,
                            int nNodes, int mpad) {
  int t = blockIdx.x * blockDim.x + threadIdx.x;   // one thread = 4 cols
  int n = t >> 6;
  int c = (t & 63) * 4;
  if (n >= mpad) return;
  float4 v = make_float4(0.f, 0.f, 0.f, 0.f);
  if (n < nNodes) v = *(const float4*)&F[(size_t)n * NFEAT + c];
  bf16x4 o;
  o[0] = (bf16_t)v.x; o[1] = (bf16_t)v.y; o[2] = (bf16_t)v.z; o[3] = (bf16_t)v.w;
  *(bf16x4*)&X[(size_t)n * KDIM + c] = o;
}

// ---------------- aggregation (gather-mean) ----------------
// one wave per node. lanes 0-31 handle even neighbors, 32-63 odd; each lane
// owns 8 cols (bf16x8 = 16B loads). Index loads pipelined one pair ahead.
__global__ __launch_bounds__(64) void k_agg(const bf16_t* __restrict__ Hin,
                                            bf16_t* __restrict__ Hout,
                                            const int* __restrict__ csr_src,
                                            const int* __restrict__ offsets,
                                            const int* __restrict__ deg,
                                            const float* __restrict__ inv_deg,
                                            int instride, int outstride) {
  const int n = blockIdx.x;
  const int lane = threadIdx.x;
  const int half = lane >> 5;
  const int l32 = lane & 31;
  const int beg = offsets[n];
  const int cnt = deg[n];
  const size_t colo = (size_t)l32 * 8;

  float acc[8] = {0.f, 0.f, 0.f, 0.f, 0.f, 0.f, 0.f, 0.f};

  int k0 = half;
  int s_cur = (k0 < cnt) ? csr_src[beg + k0] : -1;
  for (int i = 0; i < cnt; i += 2) {
    int k1 = i + 2 + half;
    int s_nxt = (k1 < cnt) ? csr_src[beg + k1] : -1;
    if (s_cur >= 0) {
      bf16x8 v = *(const bf16x8*)&Hin[(size_t)s_cur * instride + colo];
      #pragma unroll
      for (int j = 0; j < 8; ++j) acc[j] += (float)v[j];
    }
    s_cur = s_nxt;
  }

  // cross-half reduce
  #pragma unroll
  for (int j = 0; j < 8; ++j) acc[j] += __shfl_xor(acc[j], 32, 64);

  if (half == 0) {
    float w = inv_deg[n];
    bf16x8 o;
    #pragma unroll
    for (int j = 0; j < 8; ++j) o[j] = (bf16_t)(acc[j] * w);
    *(bf16x8*)&Hout[(size_t)n * outstride + NFEAT + colo] = o;
  }
}

// ---------------- GEMM: [mpad x 512] @ [512 x 256] -> bf16 out ----------------
__global__ __launch_bounds__(256, 2) void k_gemm(const bf16_t* __restrict__ A,
                                                 const bf16_t* __restrict__ BT,
                                                 const float* __restrict__ bias,
                                                 bf16_t* __restrict__ Cout,
                                                 int ostride, int relu) {
  __shared__ __align__(16) bf16_t As[2][BM * BK];
  __shared__ __align__(16) bf16_t Bs[2][BN * BK];
  const int tid  = threadIdx.x;
  const int lane = tid & 63;
  const int wave = tid >> 6;
  const int wr = wave >> 1, wc = wave & 1;    // 2x2 waves, 64x64 each
  const int m0 = blockIdx.x * BM;
  const int n0 = blockIdx.y * BN;
  const int l15 = lane & 15;
  const int lk8 = (lane >> 4) * 8;

  f32x4 acc[4][4] = {};

  auto stage = [&](int buf, int kt) {
    const int k0 = kt * BK;
    #pragma unroll
    for (int i = 0; i < 4; ++i) {
      int idx = i * 256 + tid;
      int row = idx >> 3;
      int c8  = (idx & 7) * 8;
      gload_lds16(A + (size_t)(m0 + row) * KDIM + k0 + c8,
                  (char*)&As[buf][0] + (i * 256 + wave * 64) * 16);
    }
    #pragma unroll
    for (int i = 0; i < 4; ++i) {
      int idx = i * 256 + tid;
      int row = idx >> 3;
      int c8  = (idx & 7) * 8;
      gload_lds16(BT + (size_t)(n0 + row) * KDIM + k0 + c8,
                  (char*)&Bs[buf][0] + (i * 256 + wave * 64) * 16);
    }
  };

  auto compute = [&](int buf) {
    #pragma unroll
    for (int kk = 0; kk < 2; ++kk) {
      bf16x8 af[4], bfr[4];
      #pragma unroll
      for (int m = 0; m < 4; ++m) {
        int row = wr * 64 + m * 16 + l15;
        af[m] = *(const bf16x8*)&As[buf][row * BK + kk * 32 + lk8];
      }
      #pragma unroll
      for (int n = 0; n < 4; ++n) {
        int col = wc * 64 + n * 16 + l15;
        bfr[n] = *(const bf16x8*)&Bs[buf][col * BK + kk * 32 + lk8];
      }
      #pragma unroll
      for (int m = 0; m < 4; ++m)
        #pragma unroll
        for (int n = 0; n < 4; ++n)
          acc[m][n] = __builtin_amdgcn_mfma_f32_16x16x32_bf16(af[m], bfr[n], acc[m][n], 0, 0, 0);
    }
  };

  stage(0, 0);
  __syncthreads();
  const int nt = KDIM / BK;   // 8
  int cur = 0;
  for (int t = 0; t < nt; ++t) {
    if (t + 1 < nt) stage(cur ^ 1, t + 1);
    compute(cur);
    __syncthreads();
    cur ^= 1;
  }

  #pragma unroll
  for (int n = 0; n < 4; ++n) {
    int col = n0 + wc * 64 + n * 16 + l15;
    float bv = bias[col];
    #pragma unroll
    for (int m = 0; m < 4; ++m) {
      int rbase = m0 + wr * 64 + m * 16 + (lane >> 4) * 4;
      #pragma unroll
      for (int j = 0; j < 4; ++j) {
        float v = acc[m][n][j] + bv;
        if (relu) v = fmaxf(v, 0.f);
        Cout[(size_t)(rbase + j) * ostride + col] = (bf16_t)v;
      }
    }
  }
}

// ---------------- per-edge dot via MFMA: diag(S @ D^T) ----------------
// one wave = 16 edges. A-frag: src row (lane&15); B-frag: dst row (lane&15);
// 8x mfma_16x16x32 over K=256; diagonal lanes ((l15>>2)==hi) store acc[l15&3].
__global__ __launch_bounds__(256) void k_edge_dot(const bf16_t* __restrict__ H,
                                                  const int* __restrict__ src,
                                                  const int* __restrict__ dst,
                                                  float* __restrict__ out, int nE) {
  const int wid  = (blockIdx.x * blockDim.x + threadIdx.x) >> 6;
  const int lane = threadIdx.x & 63;
  const int l15  = lane & 15;
  const int hi   = lane >> 4;
  const int e0   = wid * 16;
  if (e0 >= nE) return;
  int es = e0 + l15;
  if (es >= nE) es = nE - 1;          // clamp (loads only; store guarded)

  const int s = src[es], d = dst[es];
  const bf16_t* ps = H + (size_t)s * NFEAT + hi * 8;
  const bf16_t* pd = H + (size_t)d * NFEAT + hi * 8;

  f32x4 acc = {0.f, 0.f, 0.f, 0.f};
  #pragma unroll
  for (int ks = 0; ks < 8; ++ks) {
    bf16x8 a = *(const bf16x8*)(ps + ks * 32);
    bf16x8 b = *(const bf16x8*)(pd + ks * 32);
    acc = __builtin_amdgcn_mfma_f32_16x16x32_bf16(a, b, acc, 0, 0, 0);
  }

  // diagonal: C row = hi*4 + j, col = l15; row==col -> j = l15 - hi*4
  if ((l15 >> 2) == hi && (e0 + l15) < nE) {
    int j = l15 & 3;
    float v = acc[0];
    v = (j == 1) ? acc[1] : v;
    v = (j == 2) ? acc[2] : v;
    v = (j == 3) ? acc[3] : v;
    out[e0 + l15] = v;
  }
}

// ---------------- launcher ----------------

extern "C" void kernel_launch(void* const* d_in, const int* in_sizes, int n_in,
                              void* d_out, int out_size, void* d_ws, size_t ws_size,
                              hipStream_t stream) {
  const float* features = (const float*)d_in[0];
  const int*   src      = (const int*)d_in[1];
  const int*   dst      = (const int*)d_in[2];
  const float* Wself1   = (const float*)d_in[3];
  const float* Wneigh1  = (const float*)d_in[4];
  const float* b1       = (const float*)d_in[5];
  const float* Wself2   = (const float*)d_in[6];
  const float* Wneigh2  = (const float*)d_in[7];
  const float* b2       = (const float*)d_in[8];
  float* score = (float*)d_out;

  const int nNodes = in_sizes[0] / NFEAT;       // 20000
  const int nE     = in_sizes[1];               // 320000
  const int mpad   = ((nNodes + BM - 1) / BM) * BM;  // 20096

  char* ws = (char*)d_ws;
  size_t off = 0;
  auto alloc = [&](size_t bytes) { char* p = ws + off; off += (bytes + 255) & ~(size_t)255; return p; };
  bf16_t* Xcat1   = (bf16_t*)alloc((size_t)mpad * KDIM * 2);
  bf16_t* Xcat2   = (bf16_t*)alloc((size_t)mpad * KDIM * 2);
  bf16_t* H2      = (bf16_t*)alloc((size_t)mpad * NFEAT * 2);
  bf16_t* WT1     = (bf16_t*)alloc((size_t)NFEAT * KDIM * 2);
  bf16_t* WT2     = (bf16_t*)alloc((size_t)NFEAT * KDIM * 2);
  int*    deg     = (int*)alloc((size_t)mpad * 4);
  int*    offsets = (int*)alloc((size_t)mpad * 4);
  int*    cursor  = (int*)alloc((size_t)mpad * 4);
  float*  inv_deg = (float*)alloc((size_t)mpad * 4);
  int*    csr_src = (int*)alloc((size_t)nE * 4);
  int*    partial = (int*)alloc(1024 * 4);

  const int eb = (nE + 255) / 256;
  const int nb = (mpad + 255) / 256;     // 79 scan blocks

  // prep (also zeroes deg) — must precede k_count_deg
  k_prep_w<<<(2 * NFEAT * KDIM + 255) / 256, 256, 0, stream>>>(Wself1, Wneigh1,
                                                               Wself2, Wneigh2, WT1, WT2,
                                                               deg, mpad);
  k_cast_feat<<<(mpad * 64 + 255) / 256, 256, 0, stream>>>(features, Xcat1, nNodes, mpad);

  // graph prep
  k_count_deg<<<eb, 256, 0, stream>>>(dst, deg, nE);
  k_scan_part<<<nb, 256, 0, stream>>>(deg, partial, mpad);
  k_scan_mid<<<1, 256, 0, stream>>>(partial, nb);
  k_scan_final<<<nb, 256, 0, stream>>>(deg, partial, offsets, cursor, inv_deg, mpad);
  k_scatter<<<eb, 256, 0, stream>>>(src, dst, cursor, csr_src, nE);

  // layer 1
  k_agg<<<mpad, 64, 0, stream>>>(Xcat1, Xcat1, csr_src, offsets, deg, inv_deg, KDIM, KDIM);
  dim3 ggrid(mpad / BM, NFEAT / BN);
  k_gemm<<<ggrid, 256, 0, stream>>>(Xcat1, WT1, b1, Xcat2, KDIM, 1);

  // layer 2
  k_agg<<<mpad, 64, 0, stream>>>(Xcat2, Xcat2, csr_src, offsets, deg, inv_deg, KDIM, KDIM);
  k_gemm<<<ggrid, 256, 0, stream>>>(Xcat2, WT2, b2, H2, NFEAT, 0);

  // edge scores: one wave per 16 edges
  const int nWaves = (nE + 15) / 16;
  k_edge_dot<<<(nWaves + 3) / 4, 256, 0, stream>>>(H2, src, dst, score, nE);
}

// Round 5
// 166.503 us; speedup vs baseline: 1.3595x; 1.0514x over previous
//
#include <hip/hip_runtime.h>
#include <hip/hip_bf16.h>
#include <stdint.h>

typedef __bf16 bf16_t;
typedef __bf16 bf16x8 __attribute__((ext_vector_type(8)));
typedef __bf16 bf16x4 __attribute__((ext_vector_type(4)));
typedef float f32x4 __attribute__((ext_vector_type(4)));

#define NFEAT 256   // feature dim (both layers)
#define KDIM  512   // concat K = 2*NFEAT
#define BM 64
#define BN 128
#define BK 64

__device__ __forceinline__ void gload_lds16(const void* g, void* l) {
  __builtin_amdgcn_global_load_lds(
      (const __attribute__((address_space(1))) unsigned int*)g,
      (__attribute__((address_space(3))) unsigned int*)l, 16, 0, 0);
}

// ---------------- graph prep ----------------

__global__ void k_count_deg(const int* __restrict__ dst, int* __restrict__ deg, int nE) {
  int i = blockIdx.x * blockDim.x + threadIdx.x;
  if (i < nE) atomicAdd(&deg[dst[i]], 1);
}

// ---- device-wide scan, 3 kernels (reduce -> scan partials -> local scan) ----

__global__ __launch_bounds__(256) void k_scan_part(const int* __restrict__ deg,
                                                   int* __restrict__ partial, int n) {
  const int tid = threadIdx.x;
  int i = blockIdx.x * 256 + tid;
  int d = (i < n) ? deg[i] : 0;
  #pragma unroll
  for (int off = 32; off; off >>= 1) d += __shfl_xor(d, off, 64);
  __shared__ int ws[4];
  if ((tid & 63) == 0) ws[tid >> 6] = d;
  __syncthreads();
  if (tid == 0) partial[blockIdx.x] = ws[0] + ws[1] + ws[2] + ws[3];
}

__global__ __launch_bounds__(256) void k_scan_mid(int* __restrict__ partial, int nb) {
  __shared__ int s[256];
  const int tid = threadIdx.x;
  int d = (tid < nb) ? partial[tid] : 0;
  s[tid] = d;
  __syncthreads();
  for (int off = 1; off < 256; off <<= 1) {
    int v = (tid >= off) ? s[tid - off] : 0;
    __syncthreads();
    s[tid] += v;
    __syncthreads();
  }
  if (tid < nb) partial[tid] = s[tid] - d;   // exclusive
}

__global__ __launch_bounds__(256) void k_scan_final(const int* __restrict__ deg,
                                                    const int* __restrict__ partial,
                                                    int* __restrict__ offsets,
                                                    int* __restrict__ cursor,
                                                    float* __restrict__ inv_deg, int n) {
  __shared__ int s[256];
  const int tid = threadIdx.x;
  int i = blockIdx.x * 256 + tid;
  int d = (i < n) ? deg[i] : 0;
  s[tid] = d;
  __syncthreads();
  for (int off = 1; off < 256; off <<= 1) {
    int v = (tid >= off) ? s[tid - off] : 0;
    __syncthreads();
    s[tid] += v;
    __syncthreads();
  }
  if (i < n) {
    int excl = partial[blockIdx.x] + s[tid] - d;
    offsets[i] = excl;
    cursor[i]  = excl;
    inv_deg[i] = 1.0f / (float)(d > 1 ? d : 1);
  }
}

__global__ void k_scatter(const int* __restrict__ src, const int* __restrict__ dst,
                          int* __restrict__ cursor, int* __restrict__ csr_src, int nE) {
  int i = blockIdx.x * blockDim.x + threadIdx.x;
  if (i < nE) {
    int pos = atomicAdd(&cursor[dst[i]], 1);
    csr_src[pos] = src[i];
  }
}

// ---------------- fused prep: weights->bf16 WT, features->bf16 X, deg=0 -----
// grid covers mpad*64 threads (>= 2*256*512 and >= mpad)
__global__ void k_prep(const float* __restrict__ F,
                       const float* __restrict__ Ws1, const float* __restrict__ Wn1,
                       const float* __restrict__ Ws2, const float* __restrict__ Wn2,
                       bf16_t* __restrict__ WT1, bf16_t* __restrict__ WT2,
                       bf16_t* __restrict__ X,
                       int* __restrict__ deg, int nNodes, int mpad) {
  int t = blockIdx.x * blockDim.x + threadIdx.x;
  if (t < mpad) deg[t] = 0;
  if (t < 2 * NFEAT * KDIM) {
    int layer = t >> 17;
    int r = t & (NFEAT * KDIM - 1);
    int n = r >> 9;
    int k = r & 511;
    const float* Ws = layer ? Ws2 : Ws1;
    const float* Wn = layer ? Wn2 : Wn1;
    float v = (k < NFEAT) ? Ws[k * NFEAT + n] : Wn[(k - NFEAT) * NFEAT + n];
    (layer ? WT2 : WT1)[r] = (bf16_t)v;
  }
  // feature cast: one thread = 4 cols
  int n = t >> 6;
  int c = (t & 63) * 4;
  if (n < mpad) {
    float4 v = make_float4(0.f, 0.f, 0.f, 0.f);
    if (n < nNodes) v = *(const float4*)&F[(size_t)n * NFEAT + c];
    bf16x4 o;
    o[0] = (bf16_t)v.x; o[1] = (bf16_t)v.y; o[2] = (bf16_t)v.z; o[3] = (bf16_t)v.w;
    *(bf16x4*)&X[(size_t)n * KDIM + c] = o;
  }
}

// ---------------- aggregation (gather-mean) ----------------
// 4 waves/block, one node per wave. lanes 0-31 even neighbors, 32-63 odd;
// each lane owns 8 cols (bf16x8 = 16B loads). Index loads pipelined ahead.
__global__ __launch_bounds__(256) void k_agg(const bf16_t* __restrict__ Hin,
                                             bf16_t* __restrict__ Hout,
                                             const int* __restrict__ csr_src,
                                             const int* __restrict__ offsets,
                                             const int* __restrict__ deg,
                                             const float* __restrict__ inv_deg,
                                             int instride, int outstride) {
  const int n = blockIdx.x * 4 + (threadIdx.x >> 6);
  const int lane = threadIdx.x & 63;
  const int half = lane >> 5;
  const int l32 = lane & 31;
  const int beg = offsets[n];
  const int cnt = deg[n];
  const size_t colo = (size_t)l32 * 8;

  float acc[8] = {0.f, 0.f, 0.f, 0.f, 0.f, 0.f, 0.f, 0.f};

  int s_cur = (half < cnt) ? csr_src[beg + half] : -1;
  for (int i = 0; i < cnt; i += 2) {
    int k1 = i + 2 + half;
    int s_nxt = (k1 < cnt) ? csr_src[beg + k1] : -1;
    if (s_cur >= 0) {
      bf16x8 v = *(const bf16x8*)&Hin[(size_t)s_cur * instride + colo];
      #pragma unroll
      for (int j = 0; j < 8; ++j) acc[j] += (float)v[j];
    }
    s_cur = s_nxt;
  }

  #pragma unroll
  for (int j = 0; j < 8; ++j) acc[j] += __shfl_xor(acc[j], 32, 64);

  if (half == 0) {
    float w = inv_deg[n];
    bf16x8 o;
    #pragma unroll
    for (int j = 0; j < 8; ++j) o[j] = (bf16_t)(acc[j] * w);
    *(bf16x8*)&Hout[(size_t)n * outstride + NFEAT + colo] = o;
  }
}

// ---------------- GEMM: [mpad x 512] @ [512 x 256] -> bf16 out ----------------
// BM=64, BN=128: grid (mpad/64, 2) = 628 blocks. 4 waves (2x2), 32x64/wave.
__global__ __launch_bounds__(256, 3) void k_gemm(const bf16_t* __restrict__ A,
                                                 const bf16_t* __restrict__ BT,
                                                 const float* __restrict__ bias,
                                                 bf16_t* __restrict__ Cout,
                                                 int ostride, int relu) {
  __shared__ __align__(16) bf16_t As[2][BM * BK];
  __shared__ __align__(16) bf16_t Bs[2][BN * BK];
  const int tid  = threadIdx.x;
  const int lane = tid & 63;
  const int wave = tid >> 6;
  const int wr = wave >> 1, wc = wave & 1;    // 2x2 waves, 32x64 each
  const int m0 = blockIdx.x * BM;
  const int n0 = blockIdx.y * BN;
  const int l15 = lane & 15;
  const int lk8 = (lane >> 4) * 8;

  f32x4 acc[2][4] = {};

  auto stage = [&](int buf, int kt) {
    const int k0 = kt * BK;
    #pragma unroll
    for (int i = 0; i < 2; ++i) {          // A: 64x64 = 512 chunks
      int idx = i * 256 + tid;
      int row = idx >> 3;
      int c8  = (idx & 7) * 8;
      gload_lds16(A + (size_t)(m0 + row) * KDIM + k0 + c8,
                  (char*)&As[buf][0] + (i * 256 + wave * 64) * 16);
    }
    #pragma unroll
    for (int i = 0; i < 4; ++i) {          // B: 128x64 = 1024 chunks
      int idx = i * 256 + tid;
      int row = idx >> 3;
      int c8  = (idx & 7) * 8;
      gload_lds16(BT + (size_t)(n0 + row) * KDIM + k0 + c8,
                  (char*)&Bs[buf][0] + (i * 256 + wave * 64) * 16);
    }
  };

  auto compute = [&](int buf) {
    #pragma unroll
    for (int kk = 0; kk < 2; ++kk) {
      bf16x8 af[2], bfr[4];
      #pragma unroll
      for (int m = 0; m < 2; ++m) {
        int row = wr * 32 + m * 16 + l15;
        af[m] = *(const bf16x8*)&As[buf][row * BK + kk * 32 + lk8];
      }
      #pragma unroll
      for (int n = 0; n < 4; ++n) {
        int col = wc * 64 + n * 16 + l15;
        bfr[n] = *(const bf16x8*)&Bs[buf][col * BK + kk * 32 + lk8];
      }
      #pragma unroll
      for (int m = 0; m < 2; ++m)
        #pragma unroll
        for (int n = 0; n < 4; ++n)
          acc[m][n] = __builtin_amdgcn_mfma_f32_16x16x32_bf16(af[m], bfr[n], acc[m][n], 0, 0, 0);
    }
  };

  stage(0, 0);
  __syncthreads();
  const int nt = KDIM / BK;   // 8
  int cur = 0;
  for (int t = 0; t < nt; ++t) {
    if (t + 1 < nt) stage(cur ^ 1, t + 1);
    compute(cur);
    __syncthreads();
    cur ^= 1;
  }

  #pragma unroll
  for (int n = 0; n < 4; ++n) {
    int col = n0 + wc * 64 + n * 16 + l15;
    float bv = bias[col];
    #pragma unroll
    for (int m = 0; m < 2; ++m) {
      int rbase = m0 + wr * 32 + m * 16 + (lane >> 4) * 4;
      #pragma unroll
      for (int j = 0; j < 4; ++j) {
        float v = acc[m][n][j] + bv;
        if (relu) v = fmaxf(v, 0.f);
        Cout[(size_t)(rbase + j) * ostride + col] = (bf16_t)v;
      }
    }
  }
}

// ---------------- per-edge dot via MFMA: diag(S @ D^T) ----------------
__global__ __launch_bounds__(256) void k_edge_dot(const bf16_t* __restrict__ H,
                                                  const int* __restrict__ src,
                                                  const int* __restrict__ dst,
                                                  float* __restrict__ out, int nE) {
  const int wid  = (blockIdx.x * blockDim.x + threadIdx.x) >> 6;
  const int lane = threadIdx.x & 63;
  const int l15  = lane & 15;
  const int hi   = lane >> 4;
  const int e0   = wid * 16;
  if (e0 >= nE) return;
  int es = e0 + l15;
  if (es >= nE) es = nE - 1;          // clamp (loads only; store guarded)

  const int s = src[es], d = dst[es];
  const bf16_t* ps = H + (size_t)s * NFEAT + hi * 8;
  const bf16_t* pd = H + (size_t)d * NFEAT + hi * 8;

  f32x4 acc = {0.f, 0.f, 0.f, 0.f};
  #pragma unroll
  for (int ks = 0; ks < 8; ++ks) {
    bf16x8 a = *(const bf16x8*)(ps + ks * 32);
    bf16x8 b = *(const bf16x8*)(pd + ks * 32);
    acc = __builtin_amdgcn_mfma_f32_16x16x32_bf16(a, b, acc, 0, 0, 0);
  }

  if ((l15 >> 2) == hi && (e0 + l15) < nE) {
    int j = l15 & 3;
    float v = acc[0];
    v = (j == 1) ? acc[1] : v;
    v = (j == 2) ? acc[2] : v;
    v = (j == 3) ? acc[3] : v;
    out[e0 + l15] = v;
  }
}

// ---------------- launcher ----------------

extern "C" void kernel_launch(void* const* d_in, const int* in_sizes, int n_in,
                              void* d_out, int out_size, void* d_ws, size_t ws_size,
                              hipStream_t stream) {
  const float* features = (const float*)d_in[0];
  const int*   src      = (const int*)d_in[1];
  const int*   dst      = (const int*)d_in[2];
  const float* Wself1   = (const float*)d_in[3];
  const float* Wneigh1  = (const float*)d_in[4];
  const float* b1       = (const float*)d_in[5];
  const float* Wself2   = (const float*)d_in[6];
  const float* Wneigh2  = (const float*)d_in[7];
  const float* b2       = (const float*)d_in[8];
  float* score = (float*)d_out;

  const int nNodes = in_sizes[0] / NFEAT;       // 20000
  const int nE     = in_sizes[1];               // 320000
  const int mpad   = ((nNodes + 127) / 128) * 128;  // 20096 (mult of 128)

  char* ws = (char*)d_ws;
  size_t off = 0;
  auto alloc = [&](size_t bytes) { char* p = ws + off; off += (bytes + 255) & ~(size_t)255; return p; };
  bf16_t* Xcat1   = (bf16_t*)alloc((size_t)mpad * KDIM * 2);
  bf16_t* Xcat2   = (bf16_t*)alloc((size_t)mpad * KDIM * 2);
  bf16_t* H2      = (bf16_t*)alloc((size_t)mpad * NFEAT * 2);
  bf16_t* WT1     = (bf16_t*)alloc((size_t)NFEAT * KDIM * 2);
  bf16_t* WT2     = (bf16_t*)alloc((size_t)NFEAT * KDIM * 2);
  int*    deg     = (int*)alloc((size_t)mpad * 4);
  int*    offsets = (int*)alloc((size_t)mpad * 4);
  int*    cursor  = (int*)alloc((size_t)mpad * 4);
  float*  inv_deg = (float*)alloc((size_t)mpad * 4);
  int*    csr_src = (int*)alloc((size_t)nE * 4);
  int*    partial = (int*)alloc(1024 * 4);

  const int eb = (nE + 255) / 256;
  const int nb = (mpad + 255) / 256;     // 79 scan blocks

  // fused prep (weights, features, deg=0) — must precede k_count_deg
  k_prep<<<(mpad * 64 + 255) / 256, 256, 0, stream>>>(features, Wself1, Wneigh1,
                                                      Wself2, Wneigh2, WT1, WT2,
                                                      Xcat1, deg, nNodes, mpad);

  // graph prep
  k_count_deg<<<eb, 256, 0, stream>>>(dst, deg, nE);
  k_scan_part<<<nb, 256, 0, stream>>>(deg, partial, mpad);
  k_scan_mid<<<1, 256, 0, stream>>>(partial, nb);
  k_scan_final<<<nb, 256, 0, stream>>>(deg, partial, offsets, cursor, inv_deg, mpad);
  k_scatter<<<eb, 256, 0, stream>>>(src, dst, cursor, csr_src, nE);

  // layer 1
  k_agg<<<mpad / 4, 256, 0, stream>>>(Xcat1, Xcat1, csr_src, offsets, deg, inv_deg, KDIM, KDIM);
  dim3 ggrid(mpad / BM, NFEAT / BN);
  k_gemm<<<ggrid, 256, 0, stream>>>(Xcat1, WT1, b1, Xcat2, KDIM, 1);

  // layer 2
  k_agg<<<mpad / 4, 256, 0, stream>>>(Xcat2, Xcat2, csr_src, offsets, deg, inv_deg, KDIM, KDIM);
  k_gemm<<<ggrid, 256, 0, stream>>>(Xcat2, WT2, b2, H2, NFEAT, 0);

  // edge scores: one wave per 16 edges
  const int nWaves = (nE + 15) / 16;
  k_edge_dot<<<(nWaves + 3) / 4, 256, 0, stream>>>(H2, src, dst, score, nE);
}

// Round 6
// 157.015 us; speedup vs baseline: 1.4417x; 1.0604x over previous
//
#include <hip/hip_runtime.h>
#include <hip/hip_bf16.h>
#include <stdint.h>

typedef __bf16 bf16_t;
typedef __bf16 bf16x8 __attribute__((ext_vector_type(8)));
typedef __bf16 bf16x4 __attribute__((ext_vector_type(4)));
typedef float f32x4 __attribute__((ext_vector_type(4)));

#define NFEAT 256   // feature dim (both layers)
#define KDIM  512   // concat K = 2*NFEAT
#define BM 64
#define BN 128
#define BK 64

__device__ __forceinline__ void gload_lds16(const void* g, void* l) {
  __builtin_amdgcn_global_load_lds(
      (const __attribute__((address_space(1))) unsigned int*)g,
      (__attribute__((address_space(3))) unsigned int*)l, 16, 0, 0);
}

// ---------------- graph prep ----------------

__global__ void k_count_deg(const int* __restrict__ dst, int* __restrict__ deg, int nE) {
  int i = blockIdx.x * blockDim.x + threadIdx.x;
  if (i < nE) atomicAdd(&deg[dst[i]], 1);
}

// ---- device-wide scan, 3 kernels (reduce -> scan partials -> local scan) ----

__global__ __launch_bounds__(256) void k_scan_part(const int* __restrict__ deg,
                                                   int* __restrict__ partial, int n) {
  const int tid = threadIdx.x;
  int i = blockIdx.x * 256 + tid;
  int d = (i < n) ? deg[i] : 0;
  #pragma unroll
  for (int off = 32; off; off >>= 1) d += __shfl_xor(d, off, 64);
  __shared__ int ws[4];
  if ((tid & 63) == 0) ws[tid >> 6] = d;
  __syncthreads();
  if (tid == 0) partial[blockIdx.x] = ws[0] + ws[1] + ws[2] + ws[3];
}

__global__ __launch_bounds__(256) void k_scan_mid(int* __restrict__ partial, int nb) {
  __shared__ int s[256];
  const int tid = threadIdx.x;
  int d = (tid < nb) ? partial[tid] : 0;
  s[tid] = d;
  __syncthreads();
  for (int off = 1; off < 256; off <<= 1) {
    int v = (tid >= off) ? s[tid - off] : 0;
    __syncthreads();
    s[tid] += v;
    __syncthreads();
  }
  if (tid < nb) partial[tid] = s[tid] - d;   // exclusive
}

__global__ __launch_bounds__(256) void k_scan_final(const int* __restrict__ deg,
                                                    const int* __restrict__ partial,
                                                    int* __restrict__ offsets,
                                                    int* __restrict__ cursor,
                                                    float* __restrict__ inv_deg, int n) {
  __shared__ int s[256];
  const int tid = threadIdx.x;
  int i = blockIdx.x * 256 + tid;
  int d = (i < n) ? deg[i] : 0;
  s[tid] = d;
  __syncthreads();
  for (int off = 1; off < 256; off <<= 1) {
    int v = (tid >= off) ? s[tid - off] : 0;
    __syncthreads();
    s[tid] += v;
    __syncthreads();
  }
  if (i < n) {
    int excl = partial[blockIdx.x] + s[tid] - d;
    offsets[i] = excl;
    cursor[i]  = excl;
    inv_deg[i] = 1.0f / (float)(d > 1 ? d : 1);
  }
}

// writes csr_src (4B, for agg) and packed {src,dst,eid} (16B, for edge_dot)
__global__ void k_scatter(const int* __restrict__ src, const int* __restrict__ dst,
                          int* __restrict__ cursor, int* __restrict__ csr_src,
                          int4* __restrict__ csr_pack, int nE) {
  int i = blockIdx.x * blockDim.x + threadIdx.x;
  if (i < nE) {
    int d = dst[i];
    int s = src[i];
    int pos = atomicAdd(&cursor[d], 1);
    csr_src[pos]  = s;
    csr_pack[pos] = make_int4(s, d, i, 0);
  }
}

// ---------------- fused prep: weights->bf16 WT, features->bf16 X, deg=0 -----
__global__ void k_prep(const float* __restrict__ F,
                       const float* __restrict__ Ws1, const float* __restrict__ Wn1,
                       const float* __restrict__ Ws2, const float* __restrict__ Wn2,
                       bf16_t* __restrict__ WT1, bf16_t* __restrict__ WT2,
                       bf16_t* __restrict__ X,
                       int* __restrict__ deg, int nNodes, int mpad) {
  int t = blockIdx.x * blockDim.x + threadIdx.x;
  if (t < mpad) deg[t] = 0;
  if (t < 2 * NFEAT * KDIM) {
    int layer = t >> 17;
    int r = t & (NFEAT * KDIM - 1);
    int n = r >> 9;
    int k = r & 511;
    const float* Ws = layer ? Ws2 : Ws1;
    const float* Wn = layer ? Wn2 : Wn1;
    float v = (k < NFEAT) ? Ws[k * NFEAT + n] : Wn[(k - NFEAT) * NFEAT + n];
    (layer ? WT2 : WT1)[r] = (bf16_t)v;
  }
  int n = t >> 6;
  int c = (t & 63) * 4;
  if (n < mpad) {
    float4 v = make_float4(0.f, 0.f, 0.f, 0.f);
    if (n < nNodes) v = *(const float4*)&F[(size_t)n * NFEAT + c];
    bf16x4 o;
    o[0] = (bf16_t)v.x; o[1] = (bf16_t)v.y; o[2] = (bf16_t)v.z; o[3] = (bf16_t)v.w;
    *(bf16x4*)&X[(size_t)n * KDIM + c] = o;
  }
}

// ---------------- aggregation (gather-mean) ----------------
// half-wave (32 lanes) per node: each lane owns 8 cols (bf16x8 = 16B).
// 2 independent row loads in flight; index loads prefetched; no reduce.
__global__ __launch_bounds__(256) void k_agg(const bf16_t* __restrict__ Hin,
                                             bf16_t* __restrict__ Hout,
                                             const int* __restrict__ csr_src,
                                             const int* __restrict__ offsets,
                                             const int* __restrict__ deg,
                                             const float* __restrict__ inv_deg,
                                             int instride, int outstride) {
  const int n   = blockIdx.x * 8 + (threadIdx.x >> 5);
  const int l32 = threadIdx.x & 31;
  const int beg = offsets[n];
  const int cnt = deg[n];
  const size_t colo = (size_t)l32 * 8;

  float acc[8] = {0.f, 0.f, 0.f, 0.f, 0.f, 0.f, 0.f, 0.f};

  int s0 = (0 < cnt) ? csr_src[beg] : -1;
  int s1 = (1 < cnt) ? csr_src[beg + 1] : -1;
  for (int i = 0; i < cnt; i += 2) {
    bf16x8 v0, v1;
    const bool h0 = (s0 >= 0), h1 = (s1 >= 0);
    if (h0) v0 = *(const bf16x8*)&Hin[(size_t)s0 * instride + colo];
    if (h1) v1 = *(const bf16x8*)&Hin[(size_t)s1 * instride + colo];
    int j = i + 2;
    s0 = (j < cnt)     ? csr_src[beg + j]     : -1;
    s1 = (j + 1 < cnt) ? csr_src[beg + j + 1] : -1;
    if (h0) {
      #pragma unroll
      for (int q = 0; q < 8; ++q) acc[q] += (float)v0[q];
    }
    if (h1) {
      #pragma unroll
      for (int q = 0; q < 8; ++q) acc[q] += (float)v1[q];
    }
  }

  float w = inv_deg[n];
  bf16x8 o;
  #pragma unroll
  for (int q = 0; q < 8; ++q) o[q] = (bf16_t)(acc[q] * w);
  *(bf16x8*)&Hout[(size_t)n * outstride + NFEAT + colo] = o;
}

// ---------------- GEMM: [mpad x 512] @ [512 x 256] -> bf16 out ----------------
__global__ __launch_bounds__(256, 3) void k_gemm(const bf16_t* __restrict__ A,
                                                 const bf16_t* __restrict__ BT,
                                                 const float* __restrict__ bias,
                                                 bf16_t* __restrict__ Cout,
                                                 int ostride, int relu) {
  __shared__ __align__(16) bf16_t As[2][BM * BK];
  __shared__ __align__(16) bf16_t Bs[2][BN * BK];
  const int tid  = threadIdx.x;
  const int lane = tid & 63;
  const int wave = tid >> 6;
  const int wr = wave >> 1, wc = wave & 1;    // 2x2 waves, 32x64 each
  const int m0 = blockIdx.x * BM;
  const int n0 = blockIdx.y * BN;
  const int l15 = lane & 15;
  const int lk8 = (lane >> 4) * 8;

  f32x4 acc[2][4] = {};

  auto stage = [&](int buf, int kt) {
    const int k0 = kt * BK;
    #pragma unroll
    for (int i = 0; i < 2; ++i) {          // A: 64x64 = 512 chunks
      int idx = i * 256 + tid;
      int row = idx >> 3;
      int c8  = (idx & 7) * 8;
      gload_lds16(A + (size_t)(m0 + row) * KDIM + k0 + c8,
                  (char*)&As[buf][0] + (i * 256 + wave * 64) * 16);
    }
    #pragma unroll
    for (int i = 0; i < 4; ++i) {          // B: 128x64 = 1024 chunks
      int idx = i * 256 + tid;
      int row = idx >> 3;
      int c8  = (idx & 7) * 8;
      gload_lds16(BT + (size_t)(n0 + row) * KDIM + k0 + c8,
                  (char*)&Bs[buf][0] + (i * 256 + wave * 64) * 16);
    }
  };

  auto compute = [&](int buf) {
    #pragma unroll
    for (int kk = 0; kk < 2; ++kk) {
      bf16x8 af[2], bfr[4];
      #pragma unroll
      for (int m = 0; m < 2; ++m) {
        int row = wr * 32 + m * 16 + l15;
        af[m] = *(const bf16x8*)&As[buf][row * BK + kk * 32 + lk8];
      }
      #pragma unroll
      for (int n = 0; n < 4; ++n) {
        int col = wc * 64 + n * 16 + l15;
        bfr[n] = *(const bf16x8*)&Bs[buf][col * BK + kk * 32 + lk8];
      }
      #pragma unroll
      for (int m = 0; m < 2; ++m)
        #pragma unroll
        for (int n = 0; n < 4; ++n)
          acc[m][n] = __builtin_amdgcn_mfma_f32_16x16x32_bf16(af[m], bfr[n], acc[m][n], 0, 0, 0);
    }
  };

  stage(0, 0);
  __syncthreads();
  const int nt = KDIM / BK;   // 8
  int cur = 0;
  for (int t = 0; t < nt; ++t) {
    if (t + 1 < nt) stage(cur ^ 1, t + 1);
    compute(cur);
    __syncthreads();
    cur ^= 1;
  }

  #pragma unroll
  for (int n = 0; n < 4; ++n) {
    int col = n0 + wc * 64 + n * 16 + l15;
    float bv = bias[col];
    #pragma unroll
    for (int m = 0; m < 2; ++m) {
      int rbase = m0 + wr * 32 + m * 16 + (lane >> 4) * 4;
      #pragma unroll
      for (int j = 0; j < 4; ++j) {
        float v = acc[m][n][j] + bv;
        if (relu) v = fmaxf(v, 0.f);
        Cout[(size_t)(rbase + j) * ostride + col] = (bf16_t)v;
      }
    }
  }
}

// ---------------- per-edge dot via MFMA, CSR (dst-sorted) order -------------
// one wave = 16 CSR slots. Consecutive slots share dst rows (mean deg 16) ->
// B-side gather L1/L2-resident. out scattered via eid.
__global__ __launch_bounds__(256) void k_edge_dot(const bf16_t* __restrict__ H,
                                                  const int4* __restrict__ csr_pack,
                                                  float* __restrict__ out, int nE) {
  const int wid  = (blockIdx.x * blockDim.x + threadIdx.x) >> 6;
  const int lane = threadIdx.x & 63;
  const int l15  = lane & 15;
  const int hi   = lane >> 4;
  const int e0   = wid * 16;
  if (e0 >= nE) return;
  int pos = e0 + l15;
  if (pos >= nE) pos = nE - 1;        // clamp (loads only; store guarded)

  const int4 e = csr_pack[pos];
  const bf16_t* ps = H + (size_t)e.x * NFEAT + hi * 8;
  const bf16_t* pd = H + (size_t)e.y * NFEAT + hi * 8;

  f32x4 acc = {0.f, 0.f, 0.f, 0.f};
  #pragma unroll
  for (int ks = 0; ks < 8; ++ks) {
    bf16x8 a = *(const bf16x8*)(ps + ks * 32);
    bf16x8 b = *(const bf16x8*)(pd + ks * 32);
    acc = __builtin_amdgcn_mfma_f32_16x16x32_bf16(a, b, acc, 0, 0, 0);
  }

  if ((l15 >> 2) == hi && (e0 + l15) < nE) {
    int j = l15 & 3;
    float v = acc[0];
    v = (j == 1) ? acc[1] : v;
    v = (j == 2) ? acc[2] : v;
    v = (j == 3) ? acc[3] : v;
    out[e.z] = v;
  }
}

// ---------------- launcher ----------------

extern "C" void kernel_launch(void* const* d_in, const int* in_sizes, int n_in,
                              void* d_out, int out_size, void* d_ws, size_t ws_size,
                              hipStream_t stream) {
  const float* features = (const float*)d_in[0];
  const int*   src      = (const int*)d_in[1];
  const int*   dst      = (const int*)d_in[2];
  const float* Wself1   = (const float*)d_in[3];
  const float* Wneigh1  = (const float*)d_in[4];
  const float* b1       = (const float*)d_in[5];
  const float* Wself2   = (const float*)d_in[6];
  const float* Wneigh2  = (const float*)d_in[7];
  const float* b2       = (const float*)d_in[8];
  float* score = (float*)d_out;

  const int nNodes = in_sizes[0] / NFEAT;       // 20000
  const int nE     = in_sizes[1];               // 320000
  const int mpad   = ((nNodes + 127) / 128) * 128;  // 20096 (mult of 128)

  char* ws = (char*)d_ws;
  size_t off = 0;
  auto alloc = [&](size_t bytes) { char* p = ws + off; off += (bytes + 255) & ~(size_t)255; return p; };
  bf16_t* Xcat1   = (bf16_t*)alloc((size_t)mpad * KDIM * 2);
  bf16_t* Xcat2   = (bf16_t*)alloc((size_t)mpad * KDIM * 2);
  bf16_t* H2      = (bf16_t*)alloc((size_t)mpad * NFEAT * 2);
  bf16_t* WT1     = (bf16_t*)alloc((size_t)NFEAT * KDIM * 2);
  bf16_t* WT2     = (bf16_t*)alloc((size_t)NFEAT * KDIM * 2);
  int*    deg     = (int*)alloc((size_t)mpad * 4);
  int*    offsets = (int*)alloc((size_t)mpad * 4);
  int*    cursor  = (int*)alloc((size_t)mpad * 4);
  float*  inv_deg = (float*)alloc((size_t)mpad * 4);
  int*    csr_src = (int*)alloc((size_t)nE * 4);
  int4*   csr_pack= (int4*)alloc((size_t)nE * 16);
  int*    partial = (int*)alloc(1024 * 4);

  const int eb = (nE + 255) / 256;
  const int nb = (mpad + 255) / 256;     // 79 scan blocks

  // fused prep (weights, features, deg=0) — must precede k_count_deg
  k_prep<<<(mpad * 64 + 255) / 256, 256, 0, stream>>>(features, Wself1, Wneigh1,
                                                      Wself2, Wneigh2, WT1, WT2,
                                                      Xcat1, deg, nNodes, mpad);

  // graph prep
  k_count_deg<<<eb, 256, 0, stream>>>(dst, deg, nE);
  k_scan_part<<<nb, 256, 0, stream>>>(deg, partial, mpad);
  k_scan_mid<<<1, 256, 0, stream>>>(partial, nb);
  k_scan_final<<<nb, 256, 0, stream>>>(deg, partial, offsets, cursor, inv_deg, mpad);
  k_scatter<<<eb, 256, 0, stream>>>(src, dst, cursor, csr_src, csr_pack, nE);

  // layer 1
  k_agg<<<mpad / 8, 256, 0, stream>>>(Xcat1, Xcat1, csr_src, offsets, deg, inv_deg, KDIM, KDIM);
  dim3 ggrid(mpad / BM, NFEAT / BN);
  k_gemm<<<ggrid, 256, 0, stream>>>(Xcat1, WT1, b1, Xcat2, KDIM, 1);

  // layer 2
  k_agg<<<mpad / 8, 256, 0, stream>>>(Xcat2, Xcat2, csr_src, offsets, deg, inv_deg, KDIM, KDIM);
  k_gemm<<<ggrid, 256, 0, stream>>>(Xcat2, WT2, b2, H2, NFEAT, 0);

  // edge scores: one wave per 16 CSR slots
  const int nWaves = (nE + 15) / 16;
  k_edge_dot<<<(nWaves + 3) / 4, 256, 0, stream>>>(H2, csr_pack, score, nE);
}

// Round 7
// 152.119 us; speedup vs baseline: 1.4881x; 1.0322x over previous
//
#include <hip/hip_runtime.h>
#include <hip/hip_bf16.h>
#include <stdint.h>

typedef __bf16 bf16_t;
typedef __bf16 bf16x8 __attribute__((ext_vector_type(8)));
typedef __bf16 bf16x4 __attribute__((ext_vector_type(4)));
typedef float f32x4 __attribute__((ext_vector_type(4)));

#define NFEAT 256   // feature dim (both layers)
#define KDIM  512   // concat K = 2*NFEAT
#define BM 64
#define BN 128
#define BK 64

__device__ __forceinline__ void gload_lds16(const void* g, void* l) {
  __builtin_amdgcn_global_load_lds(
      (const __attribute__((address_space(1))) unsigned int*)g,
      (__attribute__((address_space(3))) unsigned int*)l, 16, 0, 0);
}

// ---------------- graph prep ----------------

__global__ void k_count_deg(const int* __restrict__ dst, int* __restrict__ deg, int nE) {
  int i = blockIdx.x * blockDim.x + threadIdx.x;
  if (i < nE) atomicAdd(&deg[dst[i]], 1);
}

// block sums: partial[b] = sum(deg[b*256 .. b*256+255])
__global__ __launch_bounds__(256) void k_scan_part(const int* __restrict__ deg,
                                                   int* __restrict__ partial, int n) {
  const int tid = threadIdx.x;
  int i = blockIdx.x * 256 + tid;
  int d = (i < n) ? deg[i] : 0;
  #pragma unroll
  for (int off = 32; off; off >>= 1) d += __shfl_xor(d, off, 64);
  __shared__ int ws[4];
  if ((tid & 63) == 0) ws[tid >> 6] = d;
  __syncthreads();
  if (tid == 0) partial[blockIdx.x] = ws[0] + ws[1] + ws[2] + ws[3];
}

// merged mid+final: each block scans the <=256 partials itself, then local scan
__global__ __launch_bounds__(256) void k_scan_final(const int* __restrict__ deg,
                                                    const int* __restrict__ partial,
                                                    int* __restrict__ offsets,
                                                    int* __restrict__ cursor,
                                                    float* __restrict__ inv_deg,
                                                    int n, int nb) {
  __shared__ int s[256], p[256];
  const int tid = threadIdx.x;
  // scan partials (inclusive) in p[]
  int pv = (tid < nb) ? partial[tid] : 0;
  p[tid] = pv;
  __syncthreads();
  for (int off = 1; off < 256; off <<= 1) {
    int v = (tid >= off) ? p[tid - off] : 0;
    __syncthreads();
    p[tid] += v;
    __syncthreads();
  }
  // local scan of this block's 256 degrees
  int i = blockIdx.x * 256 + tid;
  int d = (i < n) ? deg[i] : 0;
  s[tid] = d;
  __syncthreads();
  for (int off = 1; off < 256; off <<= 1) {
    int v = (tid >= off) ? s[tid - off] : 0;
    __syncthreads();
    s[tid] += v;
    __syncthreads();
  }
  if (i < n) {
    int block_excl = p[blockIdx.x] - partial[blockIdx.x];
    int excl = block_excl + s[tid] - d;
    offsets[i] = excl;
    cursor[i]  = excl;
    inv_deg[i] = 1.0f / (float)(d > 1 ? d : 1);
  }
}

// writes packed {src,dst,eid} (16B) per CSR slot
__global__ void k_scatter(const int* __restrict__ src, const int* __restrict__ dst,
                          int* __restrict__ cursor, int4* __restrict__ csr_pack, int nE) {
  int i = blockIdx.x * blockDim.x + threadIdx.x;
  if (i < nE) {
    int d = dst[i];
    int pos = atomicAdd(&cursor[d], 1);
    csr_pack[pos] = make_int4(src[i], d, i, 0);
  }
}

// ---------------- fused prep: weights->bf16 WT, features->bf16 X, deg=0 -----
__global__ void k_prep(const float* __restrict__ F,
                       const float* __restrict__ Ws1, const float* __restrict__ Wn1,
                       const float* __restrict__ Ws2, const float* __restrict__ Wn2,
                       bf16_t* __restrict__ WT1, bf16_t* __restrict__ WT2,
                       bf16_t* __restrict__ X,
                       int* __restrict__ deg, int nNodes, int mpad) {
  int t = blockIdx.x * blockDim.x + threadIdx.x;
  if (t < mpad) deg[t] = 0;
  if (t < 2 * NFEAT * KDIM) {
    int layer = t >> 17;
    int r = t & (NFEAT * KDIM - 1);
    int n = r >> 9;
    int k = r & 511;
    const float* Ws = layer ? Ws2 : Ws1;
    const float* Wn = layer ? Wn2 : Wn1;
    float v = (k < NFEAT) ? Ws[k * NFEAT + n] : Wn[(k - NFEAT) * NFEAT + n];
    (layer ? WT2 : WT1)[r] = (bf16_t)v;
  }
  int n = t >> 6;
  int c = (t & 63) * 4;
  if (n < mpad) {
    float4 v = make_float4(0.f, 0.f, 0.f, 0.f);
    if (n < nNodes) v = *(const float4*)&F[(size_t)n * NFEAT + c];
    bf16x4 o;
    o[0] = (bf16_t)v.x; o[1] = (bf16_t)v.y; o[2] = (bf16_t)v.z; o[3] = (bf16_t)v.w;
    *(bf16x4*)&X[(size_t)n * KDIM + c] = o;
  }
}

// ---------------- aggregation (gather-mean) ----------------
// half-wave (32 lanes) per node; lane owns 8 cols (16B loads).
// 4 independent row loads in flight; indices prefetched one batch ahead.
__global__ __launch_bounds__(256) void k_agg(const bf16_t* __restrict__ Hin,
                                             bf16_t* __restrict__ Hout,
                                             const int4* __restrict__ csr_pack,
                                             const int* __restrict__ offsets,
                                             const int* __restrict__ deg,
                                             const float* __restrict__ inv_deg,
                                             int instride, int outstride) {
  const int n   = blockIdx.x * 8 + (threadIdx.x >> 5);
  const int l32 = threadIdx.x & 31;
  const int beg = offsets[n];
  const int cnt = deg[n];
  const size_t colo = (size_t)l32 * 8;

  float acc[8] = {0.f, 0.f, 0.f, 0.f, 0.f, 0.f, 0.f, 0.f};

  int s[4];
  #pragma unroll
  for (int q = 0; q < 4; ++q) s[q] = (q < cnt) ? csr_pack[beg + q].x : -1;

  for (int i = 0; i < cnt; i += 4) {
    bf16x8 v[4];
    bool h[4];
    #pragma unroll
    for (int q = 0; q < 4; ++q) {
      h[q] = (s[q] >= 0);
      if (h[q]) v[q] = *(const bf16x8*)&Hin[(size_t)s[q] * instride + colo];
    }
    #pragma unroll
    for (int q = 0; q < 4; ++q) {
      int j = i + 4 + q;
      s[q] = (j < cnt) ? csr_pack[beg + j].x : -1;
    }
    #pragma unroll
    for (int q = 0; q < 4; ++q) {
      if (h[q]) {
        #pragma unroll
        for (int e = 0; e < 8; ++e) acc[e] += (float)v[q][e];
      }
    }
  }

  float w = inv_deg[n];
  bf16x8 o;
  #pragma unroll
  for (int e = 0; e < 8; ++e) o[e] = (bf16_t)(acc[e] * w);
  *(bf16x8*)&Hout[(size_t)n * outstride + NFEAT + colo] = o;
}

// ---------------- GEMM: [mpad x 512] @ [512 x 256] -> bf16 out ----------------
__global__ __launch_bounds__(256, 3) void k_gemm(const bf16_t* __restrict__ A,
                                                 const bf16_t* __restrict__ BT,
                                                 const float* __restrict__ bias,
                                                 bf16_t* __restrict__ Cout,
                                                 int ostride, int relu) {
  __shared__ __align__(16) bf16_t As[2][BM * BK];
  __shared__ __align__(16) bf16_t Bs[2][BN * BK];
  const int tid  = threadIdx.x;
  const int lane = tid & 63;
  const int wave = tid >> 6;
  const int wr = wave >> 1, wc = wave & 1;    // 2x2 waves, 32x64 each
  const int m0 = blockIdx.x * BM;
  const int n0 = blockIdx.y * BN;
  const int l15 = lane & 15;
  const int lk8 = (lane >> 4) * 8;

  f32x4 acc[2][4] = {};

  auto stage = [&](int buf, int kt) {
    const int k0 = kt * BK;
    #pragma unroll
    for (int i = 0; i < 2; ++i) {          // A: 64x64 = 512 chunks
      int idx = i * 256 + tid;
      int row = idx >> 3;
      int c8  = (idx & 7) * 8;
      gload_lds16(A + (size_t)(m0 + row) * KDIM + k0 + c8,
                  (char*)&As[buf][0] + (i * 256 + wave * 64) * 16);
    }
    #pragma unroll
    for (int i = 0; i < 4; ++i) {          // B: 128x64 = 1024 chunks
      int idx = i * 256 + tid;
      int row = idx >> 3;
      int c8  = (idx & 7) * 8;
      gload_lds16(BT + (size_t)(n0 + row) * KDIM + k0 + c8,
                  (char*)&Bs[buf][0] + (i * 256 + wave * 64) * 16);
    }
  };

  auto compute = [&](int buf) {
    #pragma unroll
    for (int kk = 0; kk < 2; ++kk) {
      bf16x8 af[2], bfr[4];
      #pragma unroll
      for (int m = 0; m < 2; ++m) {
        int row = wr * 32 + m * 16 + l15;
        af[m] = *(const bf16x8*)&As[buf][row * BK + kk * 32 + lk8];
      }
      #pragma unroll
      for (int n = 0; n < 4; ++n) {
        int col = wc * 64 + n * 16 + l15;
        bfr[n] = *(const bf16x8*)&Bs[buf][col * BK + kk * 32 + lk8];
      }
      #pragma unroll
      for (int m = 0; m < 2; ++m)
        #pragma unroll
        for (int n = 0; n < 4; ++n)
          acc[m][n] = __builtin_amdgcn_mfma_f32_16x16x32_bf16(af[m], bfr[n], acc[m][n], 0, 0, 0);
    }
  };

  stage(0, 0);
  __syncthreads();
  const int nt = KDIM / BK;   // 8
  int cur = 0;
  for (int t = 0; t < nt; ++t) {
    if (t + 1 < nt) stage(cur ^ 1, t + 1);
    compute(cur);
    __syncthreads();
    cur ^= 1;
  }

  #pragma unroll
  for (int n = 0; n < 4; ++n) {
    int col = n0 + wc * 64 + n * 16 + l15;
    float bv = bias[col];
    #pragma unroll
    for (int m = 0; m < 2; ++m) {
      int rbase = m0 + wr * 32 + m * 16 + (lane >> 4) * 4;
      #pragma unroll
      for (int j = 0; j < 4; ++j) {
        float v = acc[m][n][j] + bv;
        if (relu) v = fmaxf(v, 0.f);
        Cout[(size_t)(rbase + j) * ostride + col] = (bf16_t)v;
      }
    }
  }
}

// ---------------- per-edge dot via MFMA, CSR (dst-sorted) order -------------
__global__ __launch_bounds__(256) void k_edge_dot(const bf16_t* __restrict__ H,
                                                  const int4* __restrict__ csr_pack,
                                                  float* __restrict__ out, int nE) {
  const int wid  = (blockIdx.x * blockDim.x + threadIdx.x) >> 6;
  const int lane = threadIdx.x & 63;
  const int l15  = lane & 15;
  const int hi   = lane >> 4;
  const int e0   = wid * 16;
  if (e0 >= nE) return;
  int pos = e0 + l15;
  if (pos >= nE) pos = nE - 1;        // clamp (loads only; store guarded)

  const int4 e = csr_pack[pos];
  const bf16_t* ps = H + (size_t)e.x * NFEAT + hi * 8;
  const bf16_t* pd = H + (size_t)e.y * NFEAT + hi * 8;

  f32x4 acc = {0.f, 0.f, 0.f, 0.f};
  #pragma unroll
  for (int ks = 0; ks < 8; ++ks) {
    bf16x8 a = *(const bf16x8*)(ps + ks * 32);
    bf16x8 b = *(const bf16x8*)(pd + ks * 32);
    acc = __builtin_amdgcn_mfma_f32_16x16x32_bf16(a, b, acc, 0, 0, 0);
  }

  if ((l15 >> 2) == hi && (e0 + l15) < nE) {
    int j = l15 & 3;
    float v = acc[0];
    v = (j == 1) ? acc[1] : v;
    v = (j == 2) ? acc[2] : v;
    v = (j == 3) ? acc[3] : v;
    out[e.z] = v;
  }
}

// ---------------- launcher ----------------

extern "C" void kernel_launch(void* const* d_in, const int* in_sizes, int n_in,
                              void* d_out, int out_size, void* d_ws, size_t ws_size,
                              hipStream_t stream) {
  const float* features = (const float*)d_in[0];
  const int*   src      = (const int*)d_in[1];
  const int*   dst      = (const int*)d_in[2];
  const float* Wself1   = (const float*)d_in[3];
  const float* Wneigh1  = (const float*)d_in[4];
  const float* b1       = (const float*)d_in[5];
  const float* Wself2   = (const float*)d_in[6];
  const float* Wneigh2  = (const float*)d_in[7];
  const float* b2       = (const float*)d_in[8];
  float* score = (float*)d_out;

  const int nNodes = in_sizes[0] / NFEAT;       // 20000
  const int nE     = in_sizes[1];               // 320000
  const int mpad   = ((nNodes + 127) / 128) * 128;  // 20096 (mult of 128)

  char* ws = (char*)d_ws;
  size_t off = 0;
  auto alloc = [&](size_t bytes) { char* p = ws + off; off += (bytes + 255) & ~(size_t)255; return p; };
  bf16_t* Xcat1   = (bf16_t*)alloc((size_t)mpad * KDIM * 2);
  bf16_t* Xcat2   = (bf16_t*)alloc((size_t)mpad * KDIM * 2);
  bf16_t* H2      = (bf16_t*)alloc((size_t)mpad * NFEAT * 2);
  bf16_t* WT1     = (bf16_t*)alloc((size_t)NFEAT * KDIM * 2);
  bf16_t* WT2     = (bf16_t*)alloc((size_t)NFEAT * KDIM * 2);
  int*    deg     = (int*)alloc((size_t)mpad * 4);
  int*    offsets = (int*)alloc((size_t)mpad * 4);
  int*    cursor  = (int*)alloc((size_t)mpad * 4);
  float*  inv_deg = (float*)alloc((size_t)mpad * 4);
  int4*   csr_pack= (int4*)alloc((size_t)nE * 16);
  int*    partial = (int*)alloc(1024 * 4);

  const int eb = (nE + 255) / 256;
  const int nb = (mpad + 255) / 256;     // 79 scan blocks

  // fused prep (weights, features, deg=0) — must precede k_count_deg
  k_prep<<<(mpad * 64 + 255) / 256, 256, 0, stream>>>(features, Wself1, Wneigh1,
                                                      Wself2, Wneigh2, WT1, WT2,
                                                      Xcat1, deg, nNodes, mpad);

  // graph prep
  k_count_deg<<<eb, 256, 0, stream>>>(dst, deg, nE);
  k_scan_part<<<nb, 256, 0, stream>>>(deg, partial, mpad);
  k_scan_final<<<nb, 256, 0, stream>>>(deg, partial, offsets, cursor, inv_deg, mpad, nb);
  k_scatter<<<eb, 256, 0, stream>>>(src, dst, cursor, csr_pack, nE);

  // layer 1
  k_agg<<<mpad / 8, 256, 0, stream>>>(Xcat1, Xcat1, csr_pack, offsets, deg, inv_deg, KDIM, KDIM);
  dim3 ggrid(mpad / BM, NFEAT / BN);
  k_gemm<<<ggrid, 256, 0, stream>>>(Xcat1, WT1, b1, Xcat2, KDIM, 1);

  // layer 2
  k_agg<<<mpad / 8, 256, 0, stream>>>(Xcat2, Xcat2, csr_pack, offsets, deg, inv_deg, KDIM, KDIM);
  k_gemm<<<ggrid, 256, 0, stream>>>(Xcat2, WT2, b2, H2, NFEAT, 0);

  // edge scores: one wave per 16 CSR slots
  const int nWaves = (nE + 15) / 16;
  k_edge_dot<<<(nWaves + 3) / 4, 256, 0, stream>>>(H2, csr_pack, score, nE);
}